// Round 1
// baseline (1352.603 us; speedup 1.0000x reference)
//
#include <hip/hip_runtime.h>
#include <math.h>

// ---------------------------------------------------------------------------
// AudioFinder: gated-conv encoder x2 + VQ + linear head + max-reduce.
// All fp32 (CDNA4 has no fp32 MFMA; vector ALU).
// Activations kept in (N, T, C=80) layout throughout (C contiguous).
// ---------------------------------------------------------------------------

#define NBATCH 16

// ============================================================================
// Wide conv (160 out-ch <- 80 in-ch, k=4, stride S) fused with GLU gate:
//   out[n,t,c] = tanh(a) * sigmoid(g),  a = conv ch c, g = conv ch c+80
// Block: 128 threads, tile = 64 t x 80 channel-pairs.
// Thread: 5 pairs x 8 t. cg = tid>>3 (16), tg = tid&7 (8).
//   c = cg + 16*r (r<5),  t = t0 + tg + 8*q (q<8).
// K-loop chunked by 8 input channels; X chunk and transposed W chunk in LDS.
// ============================================================================
template<int S>
__global__ __launch_bounds__(128) void wide_gate(
    const float* __restrict__ x,   // (N, T_in, 80)
    const float* __restrict__ w,   // (160, 80, 4)
    const float* __restrict__ b,   // (160)
    float* __restrict__ out,       // (N, T_out, 80)
    int T_in, int T_out)
{
    constexpr int P = 63 * S + 4;       // input positions covered by 64 outputs
    __shared__ float xs[P * 9];         // [pos][icc], pad 9 (odd -> no bank conflict)
    __shared__ float wl[32 * 164];      // [kk][oc], kk = icc*4+j, pad 164

    const int tid = threadIdx.x;
    const int tg  = tid & 7;
    const int cg  = tid >> 3;           // 0..15
    const int n   = blockIdx.y;
    const int t0  = blockIdx.x * 64;

    float acc_a[5][8], acc_g[5][8];
#pragma unroll
    for (int r = 0; r < 5; ++r) {
        float ba = b[cg + 16 * r];
        float bg = b[80 + cg + 16 * r];
#pragma unroll
        for (int q = 0; q < 8; ++q) { acc_a[r][q] = ba; acc_g[r][q] = bg; }
    }

    const long base_in = (long)n * T_in * 80;

    for (int ic0 = 0; ic0 < 80; ic0 += 8) {
        __syncthreads();
        // ---- stage X chunk: P positions x 8 channels ----
        for (int idx = tid; idx < P * 2; idx += 128) {
            int pos = idx >> 1, half = idx & 1;
            int tpos = t0 * S + pos;
            float4 v = make_float4(0.f, 0.f, 0.f, 0.f);
            if (tpos < T_in)
                v = *(const float4*)(x + base_in + (long)tpos * 80 + ic0 + half * 4);
            float* d = &xs[pos * 9 + half * 4];
            d[0] = v.x; d[1] = v.y; d[2] = v.z; d[3] = v.w;
        }
        // ---- stage W chunk, transposed to [kk][oc] ----
        for (int f = tid; f < 160 * 8; f += 128) {
            int oc = f >> 3, k4 = f & 7;
            float4 v = *(const float4*)(w + oc * 320 + ic0 * 4 + k4 * 4);
            wl[(k4 * 4 + 0) * 164 + oc] = v.x;
            wl[(k4 * 4 + 1) * 164 + oc] = v.y;
            wl[(k4 * 4 + 2) * 164 + oc] = v.z;
            wl[(k4 * 4 + 3) * 164 + oc] = v.w;
        }
        __syncthreads();

#pragma unroll 2
        for (int icc = 0; icc < 8; ++icc) {
#pragma unroll
            for (int j = 0; j < 4; ++j) {
                const int kk = icc * 4 + j;
                float xv[8];
#pragma unroll
                for (int q = 0; q < 8; ++q)
                    xv[q] = xs[((tg + 8 * q) * S + j) * 9 + icc];
#pragma unroll
                for (int r = 0; r < 5; ++r) {
                    float wa = wl[kk * 164 + cg + 16 * r];
                    float wg = wl[kk * 164 + 80 + cg + 16 * r];
#pragma unroll
                    for (int q = 0; q < 8; ++q) {
                        acc_a[r][q] = fmaf(wa, xv[q], acc_a[r][q]);
                        acc_g[r][q] = fmaf(wg, xv[q], acc_g[r][q]);
                    }
                }
            }
        }
    }

    const long base_out = (long)n * T_out * 80;
#pragma unroll
    for (int q = 0; q < 8; ++q) {
        int t = t0 + tg + 8 * q;
        if (t < T_out) {
#pragma unroll
            for (int r = 0; r < 5; ++r) {
                int c = cg + 16 * r;
                float a  = tanhf(acc_a[r][q]);
                float gv = 1.0f / (1.0f + expf(-acc_g[r][q]));
                out[base_out + (long)t * 80 + c] = a * gv;
            }
        }
    }
}

// ============================================================================
// 1x1 conv (80<-80) + optional strided residual + optional relu.
//   out[n,t,c] = (relu?) ( b[c] + sum_ic w[c,ic]*g[n,t,ic] )
//                + res[n, res_off + t*res_stride, c]   (if res != null)
// Same thread mapping as wide_gate. W transposed to [ic][c] in LDS.
// ============================================================================
__global__ __launch_bounds__(128) void conv1x1(
    const float* __restrict__ g,    // (N, T, 80)
    const float* __restrict__ w,    // (80, 80)
    const float* __restrict__ b,    // (80)
    const float* __restrict__ res,  // (N, T_res, 80) or null
    float* __restrict__ out,        // (N, T, 80)
    int T, int T_res, int res_off, int res_stride, int do_relu)
{
    __shared__ float gs[64 * 81];   // [t_local][ic], pad 81
    __shared__ float wl[80 * 80];   // [ic][c]

    const int tid = threadIdx.x;
    const int tg  = tid & 7;
    const int cg  = tid >> 3;
    const int n   = blockIdx.y;
    const int t0  = blockIdx.x * 64;
    const long base = (long)n * T * 80;

    for (int f = tid; f < 64 * 20; f += 128) {
        int row = f / 20, i4 = f % 20;
        int t = t0 + row;
        float4 v = make_float4(0.f, 0.f, 0.f, 0.f);
        if (t < T) v = *(const float4*)(g + base + (long)t * 80 + i4 * 4);
        float* d = &gs[row * 81 + i4 * 4];
        d[0] = v.x; d[1] = v.y; d[2] = v.z; d[3] = v.w;
    }
    for (int f = tid; f < 1600; f += 128) {
        int c = f / 20, i4 = f % 20;
        float4 v = *(const float4*)(w + c * 80 + i4 * 4);
        wl[(i4 * 4 + 0) * 80 + c] = v.x;
        wl[(i4 * 4 + 1) * 80 + c] = v.y;
        wl[(i4 * 4 + 2) * 80 + c] = v.z;
        wl[(i4 * 4 + 3) * 80 + c] = v.w;
    }
    __syncthreads();

    float acc[5][8];
#pragma unroll
    for (int r = 0; r < 5; ++r) {
        float bc = b[cg + 16 * r];
#pragma unroll
        for (int q = 0; q < 8; ++q) acc[r][q] = bc;
    }

#pragma unroll 4
    for (int ic = 0; ic < 80; ++ic) {
        float xv[8];
#pragma unroll
        for (int q = 0; q < 8; ++q)
            xv[q] = gs[(tg + 8 * q) * 81 + ic];
#pragma unroll
        for (int r = 0; r < 5; ++r) {
            float wv = wl[ic * 80 + cg + 16 * r];
#pragma unroll
            for (int q = 0; q < 8; ++q)
                acc[r][q] = fmaf(wv, xv[q], acc[r][q]);
        }
    }

#pragma unroll
    for (int q = 0; q < 8; ++q) {
        int t = t0 + tg + 8 * q;
        if (t < T) {
#pragma unroll
            for (int r = 0; r < 5; ++r) {
                int c = cg + 16 * r;
                float v = acc[r][q];
                if (do_relu) v = fmaxf(v, 0.0f);
                if (res)
                    v += res[(long)n * T_res * 80 + (long)(res_off + t * res_stride) * 80 + c];
                out[base + (long)t * 80 + c] = v;
            }
        }
    }
}

// ============================================================================
// e2[e] = sum_c emb[e,c]^2
// ============================================================================
__global__ __launch_bounds__(64) void e2_kern(const float* __restrict__ emb,
                                              float* __restrict__ e2o)
{
    int e = blockIdx.x * 64 + threadIdx.x;
    if (e < 512) {
        const float4* p = (const float4*)(emb + e * 80);
        float s = 0.f;
#pragma unroll
        for (int i = 0; i < 20; ++i) {
            float4 v = p[i];
            s += v.x * v.x + v.y * v.y + v.z * v.z + v.w * v.w;
        }
        e2o[e] = s;
    }
}

// ============================================================================
// VQ argmin (512 embeddings, score = e2 - 2 x.e) + linear head + tanh.
// Block 256: 64 t positions x 4 embedding-groups (128 each).
// enc_s x-vector in registers; embedding loads are wave-uniform (broadcast).
// ============================================================================
__global__ __launch_bounds__(256) void vq_pred(
    const float* __restrict__ enc_s,  // (16, 2040, 80)
    const float* __restrict__ enc_q,  // (16, 504, 80)
    const float* __restrict__ emb,    // (512, 80)
    const float* __restrict__ e2v,    // (512)
    const float* __restrict__ w_lin,  // (2, 80)
    const float* __restrict__ b_lin,  // (2)
    float* __restrict__ pred)         // (16, 2040, 2)
{
    __shared__ float sd[4 * 64];
    __shared__ int   si[4 * 64];

    const int tid = threadIdx.x;
    const int tl  = tid & 63;
    const int eg  = tid >> 6;         // 0..3, wave-uniform
    const int n   = blockIdx.y;
    const int t   = blockIdx.x * 64 + tl;
    const bool valid = (t < 2040);

    float xv[80];
    if (valid) {
        const float* xp = enc_s + ((long)n * 2040 + t) * 80;
#pragma unroll
        for (int i = 0; i < 20; ++i) {
            float4 v = *(const float4*)(xp + 4 * i);
            xv[4 * i + 0] = v.x; xv[4 * i + 1] = v.y;
            xv[4 * i + 2] = v.z; xv[4 * i + 3] = v.w;
        }
    } else {
#pragma unroll
        for (int i = 0; i < 80; ++i) xv[i] = 0.f;
    }

    float best = 1e30f; int bi = 0;
    for (int e = eg * 128; e < eg * 128 + 128; ++e) {
        const float4* ep = (const float4*)(emb + e * 80);
        float dot = 0.f;
#pragma unroll
        for (int i = 0; i < 20; ++i) {
            float4 v = ep[i];
            dot = fmaf(xv[4 * i + 0], v.x, dot);
            dot = fmaf(xv[4 * i + 1], v.y, dot);
            dot = fmaf(xv[4 * i + 2], v.z, dot);
            dot = fmaf(xv[4 * i + 3], v.w, dot);
        }
        float score = e2v[e] - 2.0f * dot;
        if (score < best) { best = score; bi = e; }
    }
    sd[eg * 64 + tl] = best;
    si[eg * 64 + tl] = bi;
    __syncthreads();

    if (eg == 0 && valid) {
#pragma unroll
        for (int g2 = 1; g2 < 4; ++g2) {
            float d2 = sd[g2 * 64 + tl];
            int   i2 = si[g2 * 64 + tl];
            if (d2 < best || (d2 == best && i2 < bi)) { best = d2; bi = i2; }
        }
        const float* ev = emb + (long)bi * 80;
        const float* qv = nullptr;
        if (t < 2016) qv = enc_q + ((long)n * 504 + (t % 504)) * 80;
        float p0 = b_lin[0], p1 = b_lin[1];
#pragma unroll 4
        for (int c = 0; c < 80; ++c) {
            float s = ev[c] + (qv ? qv[c] : 0.f);
            p0 = fmaf(s, w_lin[c], p0);
            p1 = fmaf(s, w_lin[80 + c], p1);
        }
        long o = ((long)n * 2040 + t) * 2;
        pred[o]     = tanhf(p0);
        pred[o + 1] = tanhf(p1);
    }
}

// ============================================================================
// out[n,k] = max_t pred[n,t,k]
// ============================================================================
__global__ __launch_bounds__(256) void max_red(const float* __restrict__ pred,
                                               float* __restrict__ out)
{
    __shared__ float s0[256], s1[256];
    const int n = blockIdx.x, tid = threadIdx.x;
    float m0 = -1e30f, m1 = -1e30f;
    for (int t = tid; t < 2040; t += 256) {
        long o = ((long)n * 2040 + t) * 2;
        m0 = fmaxf(m0, pred[o]);
        m1 = fmaxf(m1, pred[o + 1]);
    }
    s0[tid] = m0; s1[tid] = m1;
    __syncthreads();
    for (int st = 128; st > 0; st >>= 1) {
        if (tid < st) {
            s0[tid] = fmaxf(s0[tid], s0[tid + st]);
            s1[tid] = fmaxf(s1[tid], s1[tid + st]);
        }
        __syncthreads();
    }
    if (tid == 0) { out[n * 2] = s0[0]; out[n * 2 + 1] = s1[0]; }
}

// ============================================================================
extern "C" void kernel_launch(void* const* d_in, const int* in_sizes, int n_in,
                              void* d_out, int out_size, void* d_ws, size_t ws_size,
                              hipStream_t stream)
{
    const float* search = (const float*)d_in[0];
    const float* query  = (const float*)d_in[1];
    const float* w_wide = (const float*)d_in[2];   // (4,160,80,4)
    const float* b_wide = (const float*)d_in[3];   // (4,160)
    const float* w_1x1  = (const float*)d_in[4];   // (4,80,80,1)
    const float* b_1x1  = (const float*)d_in[5];   // (4,80)
    const float* w_f0   = (const float*)d_in[6];   // (80,80,1)
    const float* b_f0   = (const float*)d_in[7];
    const float* w_f1   = (const float*)d_in[8];
    const float* b_f1   = (const float*)d_in[9];
    const float* emb    = (const float*)d_in[10];  // (1,512,80)
    const float* w_lin  = (const float*)d_in[11];  // (2,80)
    const float* b_lin  = (const float*)d_in[12];  // (2)
    float* out = (float*)d_out;
    float* ws  = (float*)d_ws;

    // workspace layout (floats)
    const size_t BUF_AB = 5242880;                  // 16*4095*80 = 5,241,600
    const size_t BUF_C  = 2621440;                  // 16*2046*80 = 2,618,880
    float* A    = ws;
    float* B    = A + BUF_AB;
    float* Cb   = B + BUF_AB;
    float* encS = Cb + BUF_C;                       // 16*2040*80
    float* encQ = encS + (size_t)16 * 2040 * 80;    // 16*504*80
    float* e2b  = encQ + (size_t)16 * 504 * 80;     // 512
    float* pred = e2b + 512;                        // 16*2040*2

    const dim3 blk(128);
    auto nb = [](int T) { return (unsigned)((T + 63) / 64); };

    auto encode = [&](const float* inp, int Tin, float* encOut) {
        int T0 = (Tin - 4) / 2 + 1;
        int T1 = (T0 - 4) / 2 + 1;
        int T2 = T1 - 3;
        int T3 = T2 - 3;
        // layer 0 (no residual)
        wide_gate<2><<<dim3(nb(T0), NBATCH), blk, 0, stream>>>(inp, w_wide, b_wide, A, Tin, T0);
        conv1x1<<<dim3(nb(T0), NBATCH), blk, 0, stream>>>(A, w_1x1, b_1x1, nullptr, B, T0, 0, 0, 0, 0);
        // layer 1: res[t] = x0[3 + 2t]
        wide_gate<2><<<dim3(nb(T1), NBATCH), blk, 0, stream>>>(B, w_wide + 51200, b_wide + 160, Cb, T0, T1);
        conv1x1<<<dim3(nb(T1), NBATCH), blk, 0, stream>>>(Cb, w_1x1 + 6400, b_1x1 + 80, B, A, T1, T0, 3, 2, 0);
        // layer 2: res[t] = x1[t + 3]
        wide_gate<1><<<dim3(nb(T2), NBATCH), blk, 0, stream>>>(A, w_wide + 2 * 51200, b_wide + 320, Cb, T1, T2);
        conv1x1<<<dim3(nb(T2), NBATCH), blk, 0, stream>>>(Cb, w_1x1 + 12800, b_1x1 + 160, A, B, T2, T1, 3, 1, 0);
        // layer 3: res[t] = x2[t + 3]
        wide_gate<1><<<dim3(nb(T3), NBATCH), blk, 0, stream>>>(B, w_wide + 3 * 51200, b_wide + 480, Cb, T2, T3);
        conv1x1<<<dim3(nb(T3), NBATCH), blk, 0, stream>>>(Cb, w_1x1 + 19200, b_1x1 + 240, B, A, T3, T2, 3, 1, 0);
        // final: relu(1x1) then 1x1
        conv1x1<<<dim3(nb(T3), NBATCH), blk, 0, stream>>>(A, w_f0, b_f0, nullptr, B, T3, 0, 0, 0, 1);
        conv1x1<<<dim3(nb(T3), NBATCH), blk, 0, stream>>>(B, w_f1, b_f1, nullptr, encOut, T3, 0, 0, 0, 0);
    };

    encode(search, 8192, encS);   // -> (16, 2040, 80)
    encode(query,  2048, encQ);   // -> (16, 504, 80)

    e2_kern<<<dim3(8), dim3(64), 0, stream>>>(emb, e2b);
    vq_pred<<<dim3(32, NBATCH), dim3(256), 0, stream>>>(encS, encQ, emb, e2b, w_lin, b_lin, pred);
    max_red<<<dim3(NBATCH), dim3(256), 0, stream>>>(pred, out);
}

// Round 2
// 901.818 us; speedup vs baseline: 1.4999x; 1.4999x over previous
//
#include <hip/hip_runtime.h>
#include <math.h>

// ---------------------------------------------------------------------------
// AudioFinder: gated-conv encoder x2 (merged into shared dispatches) + VQ +
// linear head + max-reduce. All fp32 (no fp32 MFMA on CDNA4; vector ALU).
// Activations in (N, T, C=80) layout (C contiguous).
// Thread tile mapping (conv kernels): 128 thr, tg=tid&7 -> t = t0+tg*8+q
// (contiguous octet -> ds_read_b128), cg=tid>>3 -> oc = cg+16r (r<5).
// ---------------------------------------------------------------------------

#define NBATCH 16

// ============================================================================
// Wide conv (160<-80, k=4, stride S) + GLU gate, both streams in one grid.
// LDS: xs[8 icc][PPAD] channel-major x chunk; wl[160 oc][36] (kk inner, b128).
// ============================================================================
template<int S>
__global__ __launch_bounds__(128) void wide_gate2(
    const float* __restrict__ xS, const float* __restrict__ xQ,
    const float* __restrict__ w,  const float* __restrict__ b,
    float* __restrict__ outS, float* __restrict__ outQ,
    int TinS, int ToutS, int TinQ, int ToutQ, int nbS)
{
    constexpr int P    = 63 * S + 4;          // input positions per 64-out tile
    constexpr int PPAD = (P + 3) & ~3;        // 132 (S=2) / 68 (S=1)
    constexpr int KX   = (S == 2) ? 20 : 12;  // per-thread x fragment (float4-mult)
    __shared__ __align__(16) float xs[8 * PPAD];
    __shared__ __align__(16) float wl[160 * 36];

    const int tid = threadIdx.x;
    const int tg  = tid & 7;
    const int cg  = tid >> 3;                 // 0..15
    const int n   = blockIdx.y;

    const float* x; float* out; int T_in, T_out, bx;
    if ((int)blockIdx.x < nbS) { x = xS; out = outS; T_in = TinS; T_out = ToutS; bx = blockIdx.x; }
    else                       { x = xQ; out = outQ; T_in = TinQ; T_out = ToutQ; bx = blockIdx.x - nbS; }
    const int t0 = bx * 64;
    const long base_in = (long)n * T_in * 80;

    float acc_a[5][8], acc_g[5][8];
#pragma unroll
    for (int r = 0; r < 5; ++r) {
        float ba = b[cg + 16 * r];
        float bg = b[80 + cg + 16 * r];
#pragma unroll
        for (int q = 0; q < 8; ++q) { acc_a[r][q] = ba; acc_g[r][q] = bg; }
    }

    for (int ic0 = 0; ic0 < 80; ic0 += 8) {
        __syncthreads();
        // stage x chunk: [icc][pos]
        for (int idx = tid; idx < P * 2; idx += 128) {
            int pos = idx >> 1, half = idx & 1;
            int tpos = t0 * S + pos;
            float4 v = make_float4(0.f, 0.f, 0.f, 0.f);
            if (tpos < T_in)
                v = *(const float4*)(x + base_in + (long)tpos * 80 + ic0 + half * 4);
            xs[(half * 4 + 0) * PPAD + pos] = v.x;
            xs[(half * 4 + 1) * PPAD + pos] = v.y;
            xs[(half * 4 + 2) * PPAD + pos] = v.z;
            xs[(half * 4 + 3) * PPAD + pos] = v.w;
        }
        // stage w chunk: [oc][kk], kk = icc*4+j (b128 in, b128 out)
        for (int f = tid; f < 160 * 8; f += 128) {
            int oc = f >> 3, k4 = f & 7;
            *(float4*)&wl[oc * 36 + k4 * 4] =
                *(const float4*)(w + oc * 320 + (ic0 + k4) * 4);
        }
        __syncthreads();

#pragma unroll 2
        for (int icc = 0; icc < 8; ++icc) {
            float4 wa4[5], wg4[5];
#pragma unroll
            for (int r = 0; r < 5; ++r) {
                wa4[r] = *(const float4*)&wl[(cg + 16 * r) * 36 + icc * 4];
                wg4[r] = *(const float4*)&wl[(cg + 16 * r + 80) * 36 + icc * 4];
            }
            float xr[KX];
#pragma unroll
            for (int i = 0; i < KX / 4; ++i)
                *(float4*)&xr[4 * i] =
                    *(const float4*)&xs[icc * PPAD + tg * 8 * S + 4 * i];
#pragma unroll
            for (int j = 0; j < 4; ++j) {
#pragma unroll
                for (int r = 0; r < 5; ++r) {
                    float wa = ((const float*)&wa4[r])[j];
                    float wg = ((const float*)&wg4[r])[j];
#pragma unroll
                    for (int q = 0; q < 8; ++q) {
                        float xv = xr[q * S + j];
                        acc_a[r][q] = fmaf(wa, xv, acc_a[r][q]);
                        acc_g[r][q] = fmaf(wg, xv, acc_g[r][q]);
                    }
                }
            }
        }
    }

    const long base_out = (long)n * T_out * 80;
#pragma unroll
    for (int q = 0; q < 8; ++q) {
        int t = t0 + tg * 8 + q;
        if (t < T_out) {
#pragma unroll
            for (int r = 0; r < 5; ++r) {
                int c = cg + 16 * r;
                float a  = tanhf(acc_a[r][q]);
                float gv = 1.0f / (1.0f + expf(-acc_g[r][q]));
                out[base_out + (long)t * 80 + c] = a * gv;
            }
        }
    }
}

// ============================================================================
// 1x1 conv (80<-80) + optional strided residual + optional relu, both streams.
// LDS: gs[80 ic][68] channel-major (b128 x-reads); wl[80 oc][84] (b128 w-reads).
// ============================================================================
__global__ __launch_bounds__(128) void conv1x1_2(
    const float* __restrict__ gS, const float* __restrict__ gQ,
    const float* __restrict__ w,  const float* __restrict__ b,
    const float* __restrict__ resS, const float* __restrict__ resQ,
    float* __restrict__ oS, float* __restrict__ oQ,
    int TS, int TQ, int TresS, int TresQ, int res_off, int res_stride,
    int do_relu, int nbS)
{
    __shared__ __align__(16) float gs[80 * 68];
    __shared__ __align__(16) float wl[80 * 84];

    const int tid = threadIdx.x;
    const int tg  = tid & 7;
    const int cg  = tid >> 3;
    const int n   = blockIdx.y;

    const float* g; const float* res; float* out; int T, T_res, bx;
    if ((int)blockIdx.x < nbS) { g = gS; res = resS; out = oS; T = TS; T_res = TresS; bx = blockIdx.x; }
    else                       { g = gQ; res = resQ; out = oQ; T = TQ; T_res = TresQ; bx = blockIdx.x - nbS; }
    const int t0 = bx * 64;
    const long base = (long)n * T * 80;

    for (int f = tid; f < 1600; f += 128) {
        int oc = f / 20, i4 = f % 20;
        *(float4*)&wl[oc * 84 + i4 * 4] = *(const float4*)(w + oc * 80 + i4 * 4);
    }
    for (int idx = tid; idx < 64 * 20; idx += 128) {
        int row = idx / 20, i4 = idx % 20;
        int t = t0 + row;
        float4 v = make_float4(0.f, 0.f, 0.f, 0.f);
        if (t < T) v = *(const float4*)(g + base + (long)t * 80 + i4 * 4);
        gs[(i4 * 4 + 0) * 68 + row] = v.x;
        gs[(i4 * 4 + 1) * 68 + row] = v.y;
        gs[(i4 * 4 + 2) * 68 + row] = v.z;
        gs[(i4 * 4 + 3) * 68 + row] = v.w;
    }
    __syncthreads();

    float acc[5][8];
#pragma unroll
    for (int r = 0; r < 5; ++r) {
        float bc = b[cg + 16 * r];
#pragma unroll
        for (int q = 0; q < 8; ++q) acc[r][q] = bc;
    }

#pragma unroll 2
    for (int ic0 = 0; ic0 < 80; ic0 += 4) {
        float4 w4[5];
#pragma unroll
        for (int r = 0; r < 5; ++r)
            w4[r] = *(const float4*)&wl[(cg + 16 * r) * 84 + ic0];
#pragma unroll
        for (int jj = 0; jj < 4; ++jj) {
            const int ic = ic0 + jj;
            float4 xa = *(const float4*)&gs[ic * 68 + tg * 8];
            float4 xb = *(const float4*)&gs[ic * 68 + tg * 8 + 4];
            float xv[8] = {xa.x, xa.y, xa.z, xa.w, xb.x, xb.y, xb.z, xb.w};
#pragma unroll
            for (int r = 0; r < 5; ++r) {
                float wv = ((const float*)&w4[r])[jj];
#pragma unroll
                for (int q = 0; q < 8; ++q)
                    acc[r][q] = fmaf(wv, xv[q], acc[r][q]);
            }
        }
    }

#pragma unroll
    for (int q = 0; q < 8; ++q) {
        int t = t0 + tg * 8 + q;
        if (t < T) {
#pragma unroll
            for (int r = 0; r < 5; ++r) {
                int c = cg + 16 * r;
                float v = acc[r][q];
                if (do_relu) v = fmaxf(v, 0.0f);
                if (res)
                    v += res[(long)n * T_res * 80 + (long)(res_off + (long)t * res_stride) * 80 + c];
                out[base + (long)t * 80 + c] = v;
            }
        }
    }
}

// ============================================================================
__global__ __launch_bounds__(64) void e2_kern(const float* __restrict__ emb,
                                              float* __restrict__ e2o)
{
    int e = blockIdx.x * 64 + threadIdx.x;
    if (e < 512) {
        const float4* p = (const float4*)(emb + e * 80);
        float s = 0.f;
#pragma unroll
        for (int i = 0; i < 20; ++i) {
            float4 v = p[i];
            s += v.x * v.x + v.y * v.y + v.z * v.z + v.w * v.w;
        }
        e2o[e] = s;
    }
}

// ============================================================================
// VQ argmin + linear head + tanh. Block 256 = 64 t x 4 emb-groups (128 each).
// X kept in 20 float4 registers (unconditional clamped load); 4 independent
// dot accumulators; emb loads wave-uniform (L1 broadcast).
// ============================================================================
__global__ __launch_bounds__(256) void vq_pred(
    const float* __restrict__ enc_s,  // (16, 2040, 80)
    const float* __restrict__ enc_q,  // (16, 504, 80)
    const float* __restrict__ emb,    // (512, 80)
    const float* __restrict__ e2v,    // (512)
    const float* __restrict__ w_lin,  // (2, 80)
    const float* __restrict__ b_lin,  // (2)
    float* __restrict__ pred)         // (16, 2040, 2)
{
    __shared__ float sd[4 * 64];
    __shared__ int   si[4 * 64];

    const int tid = threadIdx.x;
    const int tl  = tid & 63;
    const int eg  = tid >> 6;
    const int n   = blockIdx.y;
    const int t   = blockIdx.x * 64 + tl;
    const int tc  = (t < 2040) ? t : 2039;

    float4 X[20];
    {
        const float4* xp = (const float4*)(enc_s + ((long)n * 2040 + tc) * 80);
#pragma unroll
        for (int i = 0; i < 20; ++i) X[i] = xp[i];
    }

    float best = 1e30f; int bi = 0;
    const int e0 = eg * 128;
#pragma unroll 2
    for (int e = e0; e < e0 + 128; ++e) {
        const float4* ep = (const float4*)(emb + e * 80);
        float d0 = 0.f, d1 = 0.f, d2 = 0.f, d3 = 0.f;
#pragma unroll
        for (int i = 0; i < 5; ++i) {
            float4 va = ep[4 * i + 0], vb = ep[4 * i + 1];
            float4 vc = ep[4 * i + 2], vd = ep[4 * i + 3];
            d0 = fmaf(X[4 * i + 0].x, va.x, d0); d0 = fmaf(X[4 * i + 0].y, va.y, d0);
            d0 = fmaf(X[4 * i + 0].z, va.z, d0); d0 = fmaf(X[4 * i + 0].w, va.w, d0);
            d1 = fmaf(X[4 * i + 1].x, vb.x, d1); d1 = fmaf(X[4 * i + 1].y, vb.y, d1);
            d1 = fmaf(X[4 * i + 1].z, vb.z, d1); d1 = fmaf(X[4 * i + 1].w, vb.w, d1);
            d2 = fmaf(X[4 * i + 2].x, vc.x, d2); d2 = fmaf(X[4 * i + 2].y, vc.y, d2);
            d2 = fmaf(X[4 * i + 2].z, vc.z, d2); d2 = fmaf(X[4 * i + 2].w, vc.w, d2);
            d3 = fmaf(X[4 * i + 3].x, vd.x, d3); d3 = fmaf(X[4 * i + 3].y, vd.y, d3);
            d3 = fmaf(X[4 * i + 3].z, vd.z, d3); d3 = fmaf(X[4 * i + 3].w, vd.w, d3);
        }
        float score = e2v[e] - 2.0f * ((d0 + d1) + (d2 + d3));
        if (score < best) { best = score; bi = e; }
    }
    sd[eg * 64 + tl] = best;
    si[eg * 64 + tl] = bi;
    __syncthreads();

    if (eg == 0 && t < 2040) {
#pragma unroll
        for (int g2 = 1; g2 < 4; ++g2) {
            float d2v = sd[g2 * 64 + tl];
            int   i2  = si[g2 * 64 + tl];
            if (d2v < best || (d2v == best && i2 < bi)) { best = d2v; bi = i2; }
        }
        const float4* ev = (const float4*)(emb + (long)bi * 80);
        const bool hasq = (t < 2016);
        const float4* qv = hasq
            ? (const float4*)(enc_q + ((long)n * 504 + (t % 504)) * 80) : nullptr;
        float p0 = b_lin[0], p1 = b_lin[1];
#pragma unroll
        for (int i = 0; i < 20; ++i) {
            float4 e4 = ev[i];
            float4 q4 = hasq ? qv[i] : make_float4(0.f, 0.f, 0.f, 0.f);
            float4 w0 = *(const float4*)(w_lin + 4 * i);
            float4 w1 = *(const float4*)(w_lin + 80 + 4 * i);
            float sx = e4.x + q4.x, sy = e4.y + q4.y;
            float sz = e4.z + q4.z, sw = e4.w + q4.w;
            p0 = fmaf(sx, w0.x, p0); p1 = fmaf(sx, w1.x, p1);
            p0 = fmaf(sy, w0.y, p0); p1 = fmaf(sy, w1.y, p1);
            p0 = fmaf(sz, w0.z, p0); p1 = fmaf(sz, w1.z, p1);
            p0 = fmaf(sw, w0.w, p0); p1 = fmaf(sw, w1.w, p1);
        }
        long o = ((long)n * 2040 + t) * 2;
        pred[o]     = tanhf(p0);
        pred[o + 1] = tanhf(p1);
    }
}

// ============================================================================
__global__ __launch_bounds__(256) void max_red(const float* __restrict__ pred,
                                               float* __restrict__ out)
{
    __shared__ float s0[256], s1[256];
    const int n = blockIdx.x, tid = threadIdx.x;
    float m0 = -1e30f, m1 = -1e30f;
    for (int t = tid; t < 2040; t += 256) {
        long o = ((long)n * 2040 + t) * 2;
        m0 = fmaxf(m0, pred[o]);
        m1 = fmaxf(m1, pred[o + 1]);
    }
    s0[tid] = m0; s1[tid] = m1;
    __syncthreads();
    for (int st = 128; st > 0; st >>= 1) {
        if (tid < st) {
            s0[tid] = fmaxf(s0[tid], s0[tid + st]);
            s1[tid] = fmaxf(s1[tid], s1[tid + st]);
        }
        __syncthreads();
    }
    if (tid == 0) { out[n * 2] = s0[0]; out[n * 2 + 1] = s1[0]; }
}

// ============================================================================
extern "C" void kernel_launch(void* const* d_in, const int* in_sizes, int n_in,
                              void* d_out, int out_size, void* d_ws, size_t ws_size,
                              hipStream_t stream)
{
    const float* search = (const float*)d_in[0];
    const float* query  = (const float*)d_in[1];
    const float* w_wide = (const float*)d_in[2];   // (4,160,80,4)
    const float* b_wide = (const float*)d_in[3];   // (4,160)
    const float* w_1x1  = (const float*)d_in[4];   // (4,80,80,1)
    const float* b_1x1  = (const float*)d_in[5];   // (4,80)
    const float* w_f0   = (const float*)d_in[6];
    const float* b_f0   = (const float*)d_in[7];
    const float* w_f1   = (const float*)d_in[8];
    const float* b_f1   = (const float*)d_in[9];
    const float* emb    = (const float*)d_in[10];  // (1,512,80)
    const float* w_lin  = (const float*)d_in[11];  // (2,80)
    const float* b_lin  = (const float*)d_in[12];  // (2)
    float* out = (float*)d_out;
    float* ws  = (float*)d_ws;

    // workspace (floats): search ping-pong A/B/C, query QA/QB/QC.
    // Final: encS = C, encQ = QC, e2 -> A, pred -> B (all free by then).
    float* A  = ws;                 // 16*4095*80 = 5,241,600
    float* B  = A  + 5241600;       // 5,241,600
    float* C  = B  + 5241600;       // 16*2046*80 = 2,618,880
    float* QA = C  + 2618880;       // 16*1023*80 = 1,309,440
    float* QB = QA + 1309440;       // 1,309,440
    float* QC = QB + 1309440;       // 16*510*80  =   652,800

    const int T0s = 4095, T1s = 2046, T2s = 2043, T3s = 2040;
    const int T0q = 1023, T1q = 510,  T2q = 507,  T3q = 504;
    auto nb = [](int T) { return (T + 63) / 64; };
    const dim3 blk(128);
    auto grd = [&](int Ts, int Tq) { return dim3((unsigned)(nb(Ts) + nb(Tq)), NBATCH); };

    // layer 0
    wide_gate2<2><<<grd(T0s, T0q), blk, 0, stream>>>(search, query, w_wide, b_wide,
        A, QA, 8192, T0s, 2048, T0q, nb(T0s));
    conv1x1_2<<<grd(T0s, T0q), blk, 0, stream>>>(A, QA, w_1x1, b_1x1, nullptr, nullptr,
        B, QB, T0s, T0q, 0, 0, 0, 0, 0, nb(T0s));
    // layer 1: res[t] = x0[3 + 2t]
    wide_gate2<2><<<grd(T1s, T1q), blk, 0, stream>>>(B, QB, w_wide + 51200, b_wide + 160,
        C, QC, T0s, T1s, T0q, T1q, nb(T1s));
    conv1x1_2<<<grd(T1s, T1q), blk, 0, stream>>>(C, QC, w_1x1 + 6400, b_1x1 + 80, B, QB,
        A, QA, T1s, T1q, T0s, T0q, 3, 2, 0, nb(T1s));
    // layer 2: res[t] = x1[t + 3]
    wide_gate2<1><<<grd(T2s, T2q), blk, 0, stream>>>(A, QA, w_wide + 102400, b_wide + 320,
        C, QC, T1s, T2s, T1q, T2q, nb(T2s));
    conv1x1_2<<<grd(T2s, T2q), blk, 0, stream>>>(C, QC, w_1x1 + 12800, b_1x1 + 160, A, QA,
        B, QB, T2s, T2q, T1s, T1q, 3, 1, 0, nb(T2s));
    // layer 3: res[t] = x2[t + 3]
    wide_gate2<1><<<grd(T3s, T3q), blk, 0, stream>>>(B, QB, w_wide + 153600, b_wide + 480,
        C, QC, T2s, T3s, T2q, T3q, nb(T3s));
    conv1x1_2<<<grd(T3s, T3q), blk, 0, stream>>>(C, QC, w_1x1 + 19200, b_1x1 + 240, B, QB,
        A, QA, T3s, T3q, T2s, T2q, 3, 1, 0, nb(T3s));
    // final 1x1 pair
    conv1x1_2<<<grd(T3s, T3q), blk, 0, stream>>>(A, QA, w_f0, b_f0, nullptr, nullptr,
        B, QB, T3s, T3q, 0, 0, 0, 0, 1, nb(T3s));
    conv1x1_2<<<grd(T3s, T3q), blk, 0, stream>>>(B, QB, w_f1, b_f1, nullptr, nullptr,
        C, QC, T3s, T3q, 0, 0, 0, 0, 0, nb(T3s));

    e2_kern<<<dim3(8), dim3(64), 0, stream>>>(emb, A);
    vq_pred<<<dim3(32, NBATCH), dim3(256), 0, stream>>>(C, QC, emb, A, w_lin, b_lin, B);
    max_red<<<dim3(NBATCH), dim3(256), 0, stream>>>(B, out);
}

// Round 3
// 761.830 us; speedup vs baseline: 1.7755x; 1.1838x over previous
//
#include <hip/hip_runtime.h>
#include <math.h>

// ---------------------------------------------------------------------------
// AudioFinder fused: per layer one kernel (wide conv + GLU + 1x1 + residual),
// final layer also fuses the f0(relu)/f1 1x1 pair. VQ as register-blocked
// GEMM + argmin + head. All fp32 (no fp32 MFMA on CDNA4).
// Activations (N, T, 80) t-major, C contiguous.
// ---------------------------------------------------------------------------

#define NBATCH 16

__device__ __forceinline__ float fast_sigmoid(float x) {
    return 1.0f / (1.0f + __expf(-x));
}
__device__ __forceinline__ float fast_tanh(float x) {
    return 2.0f / (1.0f + __expf(-2.0f * x)) - 1.0f;
}

// ============================================================================
// Fused layer: wide conv (160<-80,k=4,stride S) + GLU -> g in LDS -> 1x1
// (80<-80) + residual; FINAL additionally: -> x3 in LDS -> relu(f0) -> LDS
// -> f1 -> out. Both search & query streams in one grid (split by blockIdx.x).
// Thread map: 128 thr; tg=tid&7 -> t=t0+tg*8+q (contiguous octet, b128);
// cg=tid>>3 -> oc = cg+16r (r<5).
// Staging: chunk ic0 step 8, prefetch next chunk to regs during compute.
// ============================================================================
template<int S, bool HAS_RES, bool FINAL>
__global__ __launch_bounds__(128, 2) void layer_fused(
    const float* __restrict__ xS, const float* __restrict__ xQ,
    const float* __restrict__ ww, const float* __restrict__ wb,   // (160,80,4),(160)
    const float* __restrict__ w1, const float* __restrict__ b1,   // (80,80),(80)
    const float* __restrict__ wf0, const float* __restrict__ bf0, // FINAL only
    const float* __restrict__ wf1, const float* __restrict__ bf1,
    float* __restrict__ outS, float* __restrict__ outQ,
    int TinS, int ToutS, int TinQ, int ToutQ, int nbS)
{
    constexpr int P    = 63 * S + 4;          // input positions per 64-out tile
    constexpr int PPAD = (P + 3) & ~3;        // 132 (S=2) / 68 (S=1)
    constexpr int KX   = (S == 2) ? 20 : 12;  // per-thread x fragment
    constexpr int NXU  = P * 2;               // float4 units per x chunk
    constexpr int XI   = (NXU + 127) / 128;   // 3 (S=2) / 2 (S=1)
    constexpr int CHUNK_F = 8 * PPAD + 160 * 36;
    constexpr int GS_F    = 80 * 68;
    constexpr int SMEM_F  = (CHUNK_F > GS_F) ? CHUNK_F : GS_F;
    __shared__ __align__(16) float smem[SMEM_F];
    float* xs = smem;              // [8 icc][PPAD]
    float* wl = smem + 8 * PPAD;   // [160 oc][36] (kk inner)
    float* gs = smem;              // [80 ic][68 t] — aliased, used after chunks

    const int tid = threadIdx.x;
    const int tg  = tid & 7;
    const int cg  = tid >> 3;      // 0..15
    const int n   = blockIdx.y;

    const float* x; float* out; int T_in, T_out, bx;
    if ((int)blockIdx.x < nbS) { x = xS; out = outS; T_in = TinS; T_out = ToutS; bx = blockIdx.x; }
    else                       { x = xQ; out = outQ; T_in = TinQ; T_out = ToutQ; bx = blockIdx.x - nbS; }
    const int t0 = bx * 64;
    const long base_in = (long)n * T_in * 80;

    // ---------------- phase 1: wide conv, prefetch double-staged ----------
    float acc_a[5][8], acc_g[5][8];
#pragma unroll
    for (int r = 0; r < 5; ++r) {
        float ba = wb[cg + 16 * r];
        float bg = wb[80 + cg + 16 * r];
#pragma unroll
        for (int q = 0; q < 8; ++q) { acc_a[r][q] = ba; acc_g[r][q] = bg; }
    }

    float4 pw[10]; float4 px[XI];
    auto loadX = [&](int ic0) {
#pragma unroll
        for (int i = 0; i < XI; ++i) {
            int u = tid + 128 * i;
            float4 v = make_float4(0.f, 0.f, 0.f, 0.f);
            if (u < NXU) {
                int pos = u >> 1, half = u & 1;
                int tpos = t0 * S + pos;
                if (tpos < T_in)
                    v = *(const float4*)(x + base_in + (long)tpos * 80 + ic0 + half * 4);
            }
            px[i] = v;
        }
    };
    auto loadW = [&](int ic0) {
#pragma unroll
        for (int i = 0; i < 10; ++i) {
            int u = tid + 128 * i;
            int oc = u >> 3, k4 = u & 7;
            pw[i] = *(const float4*)(ww + oc * 320 + (ic0 + k4) * 4);
        }
    };
    auto writeXW = [&]() {
#pragma unroll
        for (int i = 0; i < XI; ++i) {
            int u = tid + 128 * i;
            if (u < NXU) {
                int pos = u >> 1, half = u & 1;
                xs[(half * 4 + 0) * PPAD + pos] = px[i].x;
                xs[(half * 4 + 1) * PPAD + pos] = px[i].y;
                xs[(half * 4 + 2) * PPAD + pos] = px[i].z;
                xs[(half * 4 + 3) * PPAD + pos] = px[i].w;
            }
        }
#pragma unroll
        for (int i = 0; i < 10; ++i) {
            int u = tid + 128 * i;
            int oc = u >> 3, k4 = u & 7;
            *(float4*)&wl[oc * 36 + k4 * 4] = pw[i];
        }
    };

    loadX(0); loadW(0);
    for (int c = 0; c < 10; ++c) {
        __syncthreads();
        writeXW();
        __syncthreads();
        if (c < 9) { loadX((c + 1) * 8); loadW((c + 1) * 8); }
#pragma unroll 2
        for (int icc = 0; icc < 8; ++icc) {
            float4 wa4[5], wg4[5];
#pragma unroll
            for (int r = 0; r < 5; ++r) {
                wa4[r] = *(const float4*)&wl[(cg + 16 * r) * 36 + icc * 4];
                wg4[r] = *(const float4*)&wl[(cg + 16 * r + 80) * 36 + icc * 4];
            }
            float xr[KX];
#pragma unroll
            for (int i = 0; i < KX / 4; ++i)
                *(float4*)&xr[4 * i] =
                    *(const float4*)&xs[icc * PPAD + tg * 8 * S + 4 * i];
#pragma unroll
            for (int j = 0; j < 4; ++j) {
#pragma unroll
                for (int r = 0; r < 5; ++r) {
                    float wa = ((const float*)&wa4[r])[j];
                    float wg = ((const float*)&wg4[r])[j];
#pragma unroll
                    for (int q = 0; q < 8; ++q) {
                        float xv = xr[q * S + j];
                        acc_a[r][q] = fmaf(wa, xv, acc_a[r][q]);
                        acc_g[r][q] = fmaf(wg, xv, acc_g[r][q]);
                    }
                }
            }
        }
    }

    // ---------------- gate -> gs ------------------------------------------
    float gv[5][8];
#pragma unroll
    for (int r = 0; r < 5; ++r)
#pragma unroll
        for (int q = 0; q < 8; ++q)
            gv[r][q] = fast_tanh(acc_a[r][q]) * fast_sigmoid(acc_g[r][q]);

    auto store_gs = [&](float (&v)[5][8]) {
#pragma unroll
        for (int r = 0; r < 5; ++r) {
            float4 a = make_float4(v[r][0], v[r][1], v[r][2], v[r][3]);
            float4 b2 = make_float4(v[r][4], v[r][5], v[r][6], v[r][7]);
            *(float4*)&gs[(cg + 16 * r) * 68 + tg * 8]     = a;
            *(float4*)&gs[(cg + 16 * r) * 68 + tg * 8 + 4] = b2;
        }
    };
    // 1x1 (80<-80) from gs with software-pipelined L1 weight loads
    auto conv80 = [&](const float* __restrict__ W, const float* __restrict__ B,
                      float (&acc)[5][8]) {
#pragma unroll
        for (int r = 0; r < 5; ++r) {
            float bc = B[cg + 16 * r];
#pragma unroll
            for (int q = 0; q < 8; ++q) acc[r][q] = bc;
        }
        float4 wcur[5], wnxt[5];
#pragma unroll
        for (int r = 0; r < 5; ++r)
            wcur[r] = *(const float4*)(W + (cg + 16 * r) * 80);
        for (int ic0 = 0; ic0 < 80; ic0 += 4) {
            if (ic0 < 76) {
#pragma unroll
                for (int r = 0; r < 5; ++r)
                    wnxt[r] = *(const float4*)(W + (cg + 16 * r) * 80 + ic0 + 4);
            }
#pragma unroll
            for (int j = 0; j < 4; ++j) {
                float4 xa = *(const float4*)&gs[(ic0 + j) * 68 + tg * 8];
                float4 xb = *(const float4*)&gs[(ic0 + j) * 68 + tg * 8 + 4];
                float xv[8] = {xa.x, xa.y, xa.z, xa.w, xb.x, xb.y, xb.z, xb.w};
#pragma unroll
                for (int r = 0; r < 5; ++r) {
                    float wvv = ((const float*)&wcur[r])[j];
#pragma unroll
                    for (int q = 0; q < 8; ++q)
                        acc[r][q] = fmaf(wvv, xv[q], acc[r][q]);
                }
            }
#pragma unroll
            for (int r = 0; r < 5; ++r) wcur[r] = wnxt[r];
        }
    };

    __syncthreads();              // done reading xs/wl (gs aliases them)
    store_gs(gv);
    __syncthreads();

    float acc1[5][8];
    conv80(w1, b1, acc1);

    if (!FINAL) {
        const long base_out = (long)n * T_out * 80;
#pragma unroll
        for (int q = 0; q < 8; ++q) {
            int t = t0 + tg * 8 + q;
            if (t < T_out) {
#pragma unroll
                for (int r = 0; r < 5; ++r) {
                    int c = cg + 16 * r;
                    float v = acc1[r][q];
                    if (HAS_RES)
                        v += x[base_in + (long)(3 + t * S) * 80 + c];
                    out[base_out + (long)t * 80 + c] = v;
                }
            }
        }
    } else {
        // residual into x3 (guard tail loads)
        if (HAS_RES) {
#pragma unroll
            for (int q = 0; q < 8; ++q) {
                int t = t0 + tg * 8 + q;
                bool valid = (t < T_out);
#pragma unroll
                for (int r = 0; r < 5; ++r) {
                    float rv = valid ? x[base_in + (long)(3 + t * S) * 80 + cg + 16 * r] : 0.f;
                    acc1[r][q] += rv;
                }
            }
        }
        __syncthreads();          // all done reading g from gs
        store_gs(acc1);           // gs = x3
        __syncthreads();
        float acc2[5][8];
        conv80(wf0, bf0, acc2);
#pragma unroll
        for (int r = 0; r < 5; ++r)
#pragma unroll
            for (int q = 0; q < 8; ++q) acc2[r][q] = fmaxf(acc2[r][q], 0.f);
        __syncthreads();
        store_gs(acc2);           // gs = relu(f0(x3))
        __syncthreads();
        float acc3[5][8];
        conv80(wf1, bf1, acc3);
        const long base_out = (long)n * T_out * 80;
#pragma unroll
        for (int q = 0; q < 8; ++q) {
            int t = t0 + tg * 8 + q;
            if (t < T_out) {
#pragma unroll
                for (int r = 0; r < 5; ++r)
                    out[base_out + (long)t * 80 + cg + 16 * r] = acc3[r][q];
            }
        }
    }
}

// ============================================================================
__global__ __launch_bounds__(64) void e2_kern(const float* __restrict__ emb,
                                              float* __restrict__ e2o)
{
    int e = blockIdx.x * 64 + threadIdx.x;
    if (e < 512) {
        const float4* p = (const float4*)(emb + e * 80);
        float s = 0.f;
#pragma unroll
        for (int i = 0; i < 20; ++i) {
            float4 v = p[i];
            s += v.x * v.x + v.y * v.y + v.z * v.z + v.w * v.w;
        }
        e2o[e] = s;
    }
}

// ============================================================================
// VQ as register-blocked GEMM: tile 64t x 512e (e chunked by 64), 128 thr,
// thread = 8t x 4e (32 accs). X,E staged k-major in LDS. Per-thread argmin,
// LDS lexicographic reduce over 16 e-groups, fused linear head + tanh.
// ============================================================================
__global__ __launch_bounds__(128) void vq_gemm(
    const float* __restrict__ enc_s,  // (16,2040,80)
    const float* __restrict__ enc_q,  // (16,504,80)
    const float* __restrict__ emb,    // (512,80)
    const float* __restrict__ e2v,    // (512)
    const float* __restrict__ w_lin,  // (2,80)
    const float* __restrict__ b_lin,  // (2)
    float* __restrict__ pred)         // (16,2040,2)
{
    __shared__ __align__(16) float xs[80 * 64];   // [k][t]
    __shared__ __align__(16) float es[80 * 64];   // [k][e]  (aliased for reduce)

    const int tid = threadIdx.x;    // 128
    const int tx  = tid & 15;       // e-group (4 e each)
    const int ty  = tid >> 4;       // t-group (8 t each), 0..7
    const int n   = blockIdx.y;
    const int t0  = blockIdx.x * 64;

    // stage X tile (once): lane u covers (tl = u/20, k4 = u%20)
#pragma unroll
    for (int m = 0; m < 10; ++m) {
        int u  = tid * 10 + m;
        int tl = u / 20, k4 = u % 20;
        int t  = t0 + tl; if (t > 2039) t = 2039;
        float4 v = *(const float4*)(enc_s + ((long)n * 2040 + t) * 80 + k4 * 4);
        xs[(k4 * 4 + 0) * 64 + tl] = v.x;
        xs[(k4 * 4 + 1) * 64 + tl] = v.y;
        xs[(k4 * 4 + 2) * 64 + tl] = v.z;
        xs[(k4 * 4 + 3) * 64 + tl] = v.w;
    }

    float best[8]; int bi[8];
#pragma unroll
    for (int i = 0; i < 8; ++i) { best[i] = 1e30f; bi[i] = 0; }

    for (int e0 = 0; e0 < 512; e0 += 64) {
        __syncthreads();
#pragma unroll
        for (int m = 0; m < 10; ++m) {
            int u  = tid * 10 + m;
            int el = u / 20, k4 = u % 20;
            float4 v = *(const float4*)(emb + (long)(e0 + el) * 80 + k4 * 4);
            es[(k4 * 4 + 0) * 64 + el] = v.x;
            es[(k4 * 4 + 1) * 64 + el] = v.y;
            es[(k4 * 4 + 2) * 64 + el] = v.z;
            es[(k4 * 4 + 3) * 64 + el] = v.w;
        }
        __syncthreads();

        float acc[8][4];
#pragma unroll
        for (int i = 0; i < 8; ++i)
#pragma unroll
            for (int j = 0; j < 4; ++j) acc[i][j] = 0.f;

#pragma unroll 4
        for (int k = 0; k < 80; ++k) {
            float4 xa = *(const float4*)&xs[k * 64 + ty * 8];
            float4 xb = *(const float4*)&xs[k * 64 + ty * 8 + 4];
            float4 ev = *(const float4*)&es[k * 64 + tx * 4];
            float xv[8] = {xa.x, xa.y, xa.z, xa.w, xb.x, xb.y, xb.z, xb.w};
#pragma unroll
            for (int i = 0; i < 8; ++i)
#pragma unroll
                for (int j = 0; j < 4; ++j)
                    acc[i][j] = fmaf(xv[i], ((const float*)&ev)[j], acc[i][j]);
        }
        float4 e2 = *(const float4*)(e2v + e0 + tx * 4);
#pragma unroll
        for (int i = 0; i < 8; ++i)
#pragma unroll
            for (int j = 0; j < 4; ++j) {
                float s = ((const float*)&e2)[j] - 2.0f * acc[i][j];
                if (s < best[i]) { best[i] = s; bi[i] = e0 + tx * 4 + j; }
            }
    }

    // cross-e-group reduction via LDS (alias es)
    __syncthreads();
    float* rb = es;
    int*   ri = (int*)(es + 1024);
#pragma unroll
    for (int i = 0; i < 8; ++i) {
        rb[(ty * 8 + i) * 16 + tx] = best[i];
        ri[(ty * 8 + i) * 16 + tx] = bi[i];
    }
    __syncthreads();

    if (tid < 64) {
        int t = t0 + tid;
        float b = rb[tid * 16]; int ix = ri[tid * 16];
#pragma unroll
        for (int j = 1; j < 16; ++j) {
            float v = rb[tid * 16 + j]; int iv = ri[tid * 16 + j];
            if (v < b || (v == b && iv < ix)) { b = v; ix = iv; }
        }
        if (t < 2040) {
            const float4* ev = (const float4*)(emb + (long)ix * 80);
            const bool hasq = (t < 2016);
            const float4* qv = hasq
                ? (const float4*)(enc_q + ((long)n * 504 + (t % 504)) * 80) : nullptr;
            float p0 = b_lin[0], p1 = b_lin[1];
#pragma unroll
            for (int i = 0; i < 20; ++i) {
                float4 e4 = ev[i];
                float4 q4 = hasq ? qv[i] : make_float4(0.f, 0.f, 0.f, 0.f);
                float4 w0 = *(const float4*)(w_lin + 4 * i);
                float4 w1 = *(const float4*)(w_lin + 80 + 4 * i);
                float sx = e4.x + q4.x, sy = e4.y + q4.y;
                float sz = e4.z + q4.z, sw = e4.w + q4.w;
                p0 = fmaf(sx, w0.x, p0); p1 = fmaf(sx, w1.x, p1);
                p0 = fmaf(sy, w0.y, p0); p1 = fmaf(sy, w1.y, p1);
                p0 = fmaf(sz, w0.z, p0); p1 = fmaf(sz, w1.z, p1);
                p0 = fmaf(sw, w0.w, p0); p1 = fmaf(sw, w1.w, p1);
            }
            long o = ((long)n * 2040 + t) * 2;
            pred[o]     = fast_tanh(p0);
            pred[o + 1] = fast_tanh(p1);
        }
    }
}

// ============================================================================
__global__ __launch_bounds__(256) void max_red(const float* __restrict__ pred,
                                               float* __restrict__ out)
{
    __shared__ float s0[256], s1[256];
    const int n = blockIdx.x, tid = threadIdx.x;
    float m0 = -1e30f, m1 = -1e30f;
    for (int t = tid; t < 2040; t += 256) {
        long o = ((long)n * 2040 + t) * 2;
        m0 = fmaxf(m0, pred[o]);
        m1 = fmaxf(m1, pred[o + 1]);
    }
    s0[tid] = m0; s1[tid] = m1;
    __syncthreads();
    for (int st = 128; st > 0; st >>= 1) {
        if (tid < st) {
            s0[tid] = fmaxf(s0[tid], s0[tid + st]);
            s1[tid] = fmaxf(s1[tid], s1[tid + st]);
        }
        __syncthreads();
    }
    if (tid == 0) { out[n * 2] = s0[0]; out[n * 2 + 1] = s1[0]; }
}

// ============================================================================
extern "C" void kernel_launch(void* const* d_in, const int* in_sizes, int n_in,
                              void* d_out, int out_size, void* d_ws, size_t ws_size,
                              hipStream_t stream)
{
    const float* search = (const float*)d_in[0];
    const float* query  = (const float*)d_in[1];
    const float* w_wide = (const float*)d_in[2];   // (4,160,80,4)
    const float* b_wide = (const float*)d_in[3];   // (4,160)
    const float* w_1x1  = (const float*)d_in[4];   // (4,80,80,1)
    const float* b_1x1  = (const float*)d_in[5];   // (4,80)
    const float* w_f0   = (const float*)d_in[6];
    const float* b_f0   = (const float*)d_in[7];
    const float* w_f1   = (const float*)d_in[8];
    const float* b_f1   = (const float*)d_in[9];
    const float* emb    = (const float*)d_in[10];  // (1,512,80)
    const float* w_lin  = (const float*)d_in[11];  // (2,80)
    const float* b_lin  = (const float*)d_in[12];  // (2)
    float* out = (float*)d_out;
    float* ws  = (float*)d_ws;

    // workspace (floats). Flow: L0: in->A/QA; L1: A->B; L2: B->C; L3: C->A.
    // Then e2->B, pred->C.
    float* A  = ws;                 // 5,241,600
    float* B  = A  + 5241600;       // 5,241,600
    float* C  = B  + 5241600;       // 2,618,880
    float* QA = C  + 2618880;       // 1,309,440
    float* QB = QA + 1309440;       // 1,309,440
    float* QC = QB + 1309440;       //   652,800

    const int T0s = 4095, T1s = 2046, T2s = 2043, T3s = 2040;
    const int T0q = 1023, T1q = 510,  T2q = 507,  T3q = 504;
    auto nb = [](int T) { return (T + 63) / 64; };
    const dim3 blk(128);
    auto grd = [&](int Ts, int Tq) { return dim3((unsigned)(nb(Ts) + nb(Tq)), NBATCH); };

    layer_fused<2, false, false><<<grd(T0s, T0q), blk, 0, stream>>>(
        search, query, w_wide, b_wide, w_1x1, b_1x1,
        nullptr, nullptr, nullptr, nullptr,
        A, QA, 8192, T0s, 2048, T0q, nb(T0s));
    layer_fused<2, true, false><<<grd(T1s, T1q), blk, 0, stream>>>(
        A, QA, w_wide + 51200, b_wide + 160, w_1x1 + 6400, b_1x1 + 80,
        nullptr, nullptr, nullptr, nullptr,
        B, QB, T0s, T1s, T0q, T1q, nb(T1s));
    layer_fused<1, true, false><<<grd(T2s, T2q), blk, 0, stream>>>(
        B, QB, w_wide + 102400, b_wide + 320, w_1x1 + 12800, b_1x1 + 160,
        nullptr, nullptr, nullptr, nullptr,
        C, QC, T1s, T2s, T1q, T2q, nb(T2s));
    layer_fused<1, true, true><<<grd(T3s, T3q), blk, 0, stream>>>(
        C, QC, w_wide + 153600, b_wide + 480, w_1x1 + 19200, b_1x1 + 240,
        w_f0, b_f0, w_f1, b_f1,
        A, QA, T2s, T3s, T2q, T3q, nb(T3s));

    e2_kern<<<dim3(8), dim3(64), 0, stream>>>(emb, B);
    vq_gemm<<<dim3(32, NBATCH), dim3(128), 0, stream>>>(A, QA, emb, B, w_lin, b_lin, C);
    max_red<<<dim3(NBATCH), dim3(256), 0, stream>>>(C, out);
}

// Round 4
// 354.066 us; speedup vs baseline: 3.8202x; 2.1517x over previous
//
#include <hip/hip_runtime.h>
#include <math.h>

// ---------------------------------------------------------------------------
// AudioFinder, MFMA edition.
// Encoder layers run as bf16 MFMA GEMMs (split-A: x = hi+lo bf16; W single
// bf16, pre-packed k'-major where k' = j*80+ic so im2col rows == x rows).
// Gate/1x1/residual/f0/f1 fused per layer. VQ/head/max stay fp32.
// ---------------------------------------------------------------------------

#define NBATCH 16

typedef __attribute__((ext_vector_type(8))) short s16x8;
typedef __attribute__((ext_vector_type(4))) float f32x4;

__device__ __forceinline__ float fast_sigmoid(float x) {
    return 1.0f / (1.0f + __expf(-x));
}
__device__ __forceinline__ float fast_tanh(float x) {
    return 2.0f / (1.0f + __expf(-2.0f * x)) - 1.0f;
}
__device__ __forceinline__ unsigned short f2bf(float f) {
    unsigned int u = __float_as_uint(f);
    return (unsigned short)((u + 0x7FFFu + ((u >> 16) & 1u)) >> 16);
}
__device__ __forceinline__ float bf2f(unsigned short h) {
    return __uint_as_float((unsigned int)h << 16);
}

// ============================================================================
// One-time weight pre-pack to bf16:
//  WW[l][oc][k'=j*80+ic] <- w_wide[l][oc][ic][j]   (4*160*320)
//  W1[l][oc][ic], F0[oc][ic], F1[oc][ic]
// ============================================================================
__global__ __launch_bounds__(256) void pack_w(
    const float* __restrict__ w_wide, const float* __restrict__ w_1x1,
    const float* __restrict__ wf0,    const float* __restrict__ wf1,
    unsigned short* __restrict__ WW, unsigned short* __restrict__ W1,
    unsigned short* __restrict__ F0, unsigned short* __restrict__ F1)
{
    int i = blockIdx.x * 256 + threadIdx.x;
    if (i < 204800) {
        int l = i / 51200, r = i % 51200, oc = r / 320, k = r % 320;
        int j = k / 80, ic = k % 80;
        WW[i] = f2bf(w_wide[l * 51200 + oc * 320 + ic * 4 + j]);
    } else if (i < 230400) {
        W1[i - 204800] = f2bf(w_1x1[i - 204800]);
    } else if (i < 236800) {
        F0[i - 230400] = f2bf(wf0[i - 230400]);
    } else if (i < 243200) {
        F1[i - 236800] = f2bf(wf1[i - 236800]);
    }
}

// ============================================================================
// Fused encoder layer, MFMA. Block = 256 thr (4 waves), tile = 64 t x 160 oc.
// wave = m-tile (16 t); each wave does all 10 n-tiles. K = 320 in W-chunks
// of 96/96/96/32 (x tile stays resident whole time, split hi/lo, and for
// S=2 parity-split so A-frag rows are stride-1).
// Frag layouts (verified, learn_hip m89/m120): A/B lane: [m|n = lane&15]
// [k = (lane>>4)*8 + j]; D: col = lane&15 (n), row = (lane>>4)*4 + reg (m).
// ============================================================================
template<int S, bool HAS_RES, bool FINAL>
__global__ __launch_bounds__(256, 2) void enc_layer(
    const float* __restrict__ xS, const float* __restrict__ xQ,
    const unsigned short* __restrict__ ww,  // (160,320) k'-major bf16
    const float* __restrict__ wb,           // (160)
    const unsigned short* __restrict__ w1p, // (80,80) bf16
    const float* __restrict__ b1,           // (80)
    const unsigned short* __restrict__ f0p, const float* __restrict__ bf0,
    const unsigned short* __restrict__ f1p, const float* __restrict__ bf1,
    float* __restrict__ outS, float* __restrict__ outQ,
    int TinS, int ToutS, int TinQ, int ToutQ, int nbS)
{
    constexpr int P    = 63 * S + 4;
    constexpr int NPAR = (S == 2) ? 2 : 1;
    constexpr int HALF = (S == 2) ? 65 : P;
    constexpr int XROW = 88;                 // bf16; 176 B rows (16B-mult)
    constexpr int XPREC = NPAR * HALF * XROW;
    constexpr int GROW = 104;                // 208 B rows
    constexpr int GA   = 64 * GROW;
    constexpr int R1   = (2 * XPREC > 2 * GA) ? 2 * XPREC : 2 * GA;
    constexpr int WROW = 104;
    __shared__ unsigned short smem[R1 + 160 * WROW];
    unsigned short* xs = smem;               // hi [par][HALF][XROW], lo at +XPREC
    unsigned short* gs = smem;               // hi [64][GROW], lo at +GA
    unsigned short* wl = smem + R1;          // [160][WROW]

    const int tid  = threadIdx.x;
    const int wave = tid >> 6;
    const int lane = tid & 63;
    const int m    = lane & 15;
    const int quad = lane >> 4;
    const int n_   = blockIdx.y;

    const float* x; float* out; int T_in, T_out, bx;
    if ((int)blockIdx.x < nbS) { x = xS; out = outS; T_in = TinS; T_out = ToutS; bx = blockIdx.x; }
    else                       { x = xQ; out = outQ; T_in = TinQ; T_out = ToutQ; bx = blockIdx.x - nbS; }
    const int t0 = bx * 64;
    const long base_in = (long)n_ * T_in * 80;

    // ---- stage x tile once: split bf16 hi/lo, parity rows for S=2 ----
    for (int u = tid; u < P * 20; u += 256) {
        int pos = u / 20, c4 = u % 20;
        int tp = t0 * S + pos;
        if (tp > T_in - 1) tp = T_in - 1;   // clamp: only affects discarded tail rows
        float4 v = *(const float4*)(x + base_in + (long)tp * 80 + c4 * 4);
        int row = (S == 2) ? (pos >> 1) : pos;
        int par = (S == 2) ? (pos & 1) : 0;
        int o = (par * HALF + row) * XROW + c4 * 4;
        unsigned short h0 = f2bf(v.x), h1 = f2bf(v.y), h2 = f2bf(v.z), h3 = f2bf(v.w);
        unsigned short l0 = f2bf(v.x - bf2f(h0)), l1 = f2bf(v.y - bf2f(h1));
        unsigned short l2 = f2bf(v.z - bf2f(h2)), l3 = f2bf(v.w - bf2f(h3));
        *(unsigned int*)&xs[o]             = (unsigned int)h0 | ((unsigned int)h1 << 16);
        *(unsigned int*)&xs[o + 2]         = (unsigned int)h2 | ((unsigned int)h3 << 16);
        *(unsigned int*)&xs[XPREC + o]     = (unsigned int)l0 | ((unsigned int)l1 << 16);
        *(unsigned int*)&xs[XPREC + o + 2] = (unsigned int)l2 | ((unsigned int)l3 << 16);
    }

    f32x4 acc[10];
#pragma unroll
    for (int i = 0; i < 10; ++i) acc[i] = (f32x4){0.f, 0.f, 0.f, 0.f};

    const int mrow = wave * 16 + m;

    // ---- wide conv: 4 W-chunks (96,96,96,32 k), 10 ksteps total ----
#pragma unroll
    for (int s = 0; s < 4; ++s) {
        const int KS = (s < 3) ? 96 : 32;
        const int nseg = KS / 8;
        __syncthreads();
        for (int u = tid; u < 160 * nseg; u += 256) {
            int row = u / nseg, seg = u % nseg;
            *(uint4*)&wl[row * WROW + seg * 8] =
                *(const uint4*)(ww + row * 320 + s * 96 + seg * 8);
        }
        __syncthreads();
        const int nkb = KS / 32;
#pragma unroll
        for (int kbi = 0; kbi < nkb; ++kbi) {
            const int kqq = s * 96 + kbi * 32 + quad * 8;
            const int j = kqq / 80, ic0 = kqq % 80;
            int row, par;
            if (S == 2) { par = j & 1; row = mrow + (j >> 1); }
            else        { par = 0;     row = mrow + j; }
            const int xo = (par * HALF + row) * XROW + ic0;
            s16x8 ahi = *(const s16x8*)&xs[xo];
            s16x8 alo = *(const s16x8*)&xs[XPREC + xo];
            const int wko = kbi * 32 + quad * 8;
#pragma unroll
            for (int nt = 0; nt < 10; ++nt) {
                s16x8 b = *(const s16x8*)&wl[(nt * 16 + m) * WROW + wko];
                acc[nt] = __builtin_amdgcn_mfma_f32_16x16x32_bf16(alo, b, acc[nt], 0, 0, 0);
                acc[nt] = __builtin_amdgcn_mfma_f32_16x16x32_bf16(ahi, b, acc[nt], 0, 0, 0);
            }
        }
    }

    // ---- gate -> gs (bf16 split), zero K-pad cols 80..95 ----
    __syncthreads();                       // all waves done reading xs (gs aliases)
    const int trow = wave * 16 + quad * 4;
#pragma unroll
    for (int nt = 0; nt < 5; ++nt) {
        const int c = nt * 16 + m;
        const float ba = wb[c], bg = wb[80 + c];
#pragma unroll
        for (int r = 0; r < 4; ++r) {
            float a = acc[nt][r] + ba;
            float g = acc[nt + 5][r] + bg;
            float gv = fast_tanh(a) * fast_sigmoid(g);
            unsigned short h = f2bf(gv);
            unsigned short l = f2bf(gv - bf2f(h));
            gs[(trow + r) * GROW + c]      = h;
            gs[GA + (trow + r) * GROW + c] = l;
        }
    }
    for (int u = tid; u < 1024; u += 256) {
        int arr = u >> 9, rw = (u >> 3) & 63, cc = (u & 7) * 2;
        *(unsigned int*)&gs[arr * GA + rw * GROW + 80 + cc] = 0u;
    }
    __syncthreads();

    // ---- 1x1 (80<-80) via MFMA, K padded to 96 (A is zero there) ----
    for (int u = tid; u < 800; u += 256) {
        int row = u / 10, seg = u % 10;
        *(uint4*)&wl[row * WROW + seg * 8] = *(const uint4*)(w1p + row * 80 + seg * 8);
    }
    __syncthreads();
    f32x4 a1[5];
#pragma unroll
    for (int i = 0; i < 5; ++i) a1[i] = (f32x4){0.f, 0.f, 0.f, 0.f};
#pragma unroll
    for (int kb = 0; kb < 3; ++kb) {
        const int k0 = kb * 32 + quad * 8;
        s16x8 ghi = *(const s16x8*)&gs[(wave * 16 + m) * GROW + k0];
        s16x8 glo = *(const s16x8*)&gs[GA + (wave * 16 + m) * GROW + k0];
#pragma unroll
        for (int nt = 0; nt < 5; ++nt) {
            s16x8 b = *(const s16x8*)&wl[(nt * 16 + m) * WROW + k0];
            a1[nt] = __builtin_amdgcn_mfma_f32_16x16x32_bf16(glo, b, a1[nt], 0, 0, 0);
            a1[nt] = __builtin_amdgcn_mfma_f32_16x16x32_bf16(ghi, b, a1[nt], 0, 0, 0);
        }
    }

    if (!FINAL) {
        const long base_out = (long)n_ * T_out * 80;
#pragma unroll
        for (int r = 0; r < 4; ++r) {
            int tg = t0 + trow + r;
            if (tg < T_out) {
#pragma unroll
                for (int nt = 0; nt < 5; ++nt) {
                    const int c = nt * 16 + m;
                    float v = a1[nt][r] + b1[c];
                    if (HAS_RES)
                        v += x[base_in + (long)(3 + (long)tg * S) * 80 + c];
                    out[base_out + (long)tg * 80 + c] = v;
                }
            }
        }
    } else {
        // x3 = a1 + b1 + residual (clamped for tail rows)
        float x3[5][4];
#pragma unroll
        for (int r = 0; r < 4; ++r) {
            int tg = t0 + trow + r;
            int tc = (tg < T_out) ? tg : (T_out - 1);
#pragma unroll
            for (int nt = 0; nt < 5; ++nt) {
                const int c = nt * 16 + m;
                float v = a1[nt][r] + b1[c];
                if (HAS_RES)
                    v += x[base_in + (long)(3 + (long)tc * S) * 80 + c];
                x3[nt][r] = v;
            }
        }
        __syncthreads();                   // wl (w1) + gs (g) reads all done
#pragma unroll
        for (int nt = 0; nt < 5; ++nt)
#pragma unroll
            for (int r = 0; r < 4; ++r) {
                const int c = nt * 16 + m;
                unsigned short h = f2bf(x3[nt][r]);
                unsigned short l = f2bf(x3[nt][r] - bf2f(h));
                gs[(trow + r) * GROW + c]      = h;
                gs[GA + (trow + r) * GROW + c] = l;
            }
        for (int u = tid; u < 800; u += 256) {
            int row = u / 10, seg = u % 10;
            *(uint4*)&wl[row * WROW + seg * 8] = *(const uint4*)(f0p + row * 80 + seg * 8);
        }
        __syncthreads();
        f32x4 a2[5];
#pragma unroll
        for (int i = 0; i < 5; ++i) a2[i] = (f32x4){0.f, 0.f, 0.f, 0.f};
#pragma unroll
        for (int kb = 0; kb < 3; ++kb) {
            const int k0 = kb * 32 + quad * 8;
            s16x8 ghi = *(const s16x8*)&gs[(wave * 16 + m) * GROW + k0];
            s16x8 glo = *(const s16x8*)&gs[GA + (wave * 16 + m) * GROW + k0];
#pragma unroll
            for (int nt = 0; nt < 5; ++nt) {
                s16x8 b = *(const s16x8*)&wl[(nt * 16 + m) * WROW + k0];
                a2[nt] = __builtin_amdgcn_mfma_f32_16x16x32_bf16(glo, b, a2[nt], 0, 0, 0);
                a2[nt] = __builtin_amdgcn_mfma_f32_16x16x32_bf16(ghi, b, a2[nt], 0, 0, 0);
            }
        }
        float r2[5][4];
#pragma unroll
        for (int nt = 0; nt < 5; ++nt)
#pragma unroll
            for (int r = 0; r < 4; ++r)
                r2[nt][r] = fmaxf(a2[nt][r] + bf0[nt * 16 + m], 0.f);
        __syncthreads();                   // f0 wl reads done
#pragma unroll
        for (int nt = 0; nt < 5; ++nt)
#pragma unroll
            for (int r = 0; r < 4; ++r) {
                const int c = nt * 16 + m;
                unsigned short h = f2bf(r2[nt][r]);
                unsigned short l = f2bf(r2[nt][r] - bf2f(h));
                gs[(trow + r) * GROW + c]      = h;
                gs[GA + (trow + r) * GROW + c] = l;
            }
        for (int u = tid; u < 800; u += 256) {
            int row = u / 10, seg = u % 10;
            *(uint4*)&wl[row * WROW + seg * 8] = *(const uint4*)(f1p + row * 80 + seg * 8);
        }
        __syncthreads();
        f32x4 a3[5];
#pragma unroll
        for (int i = 0; i < 5; ++i) a3[i] = (f32x4){0.f, 0.f, 0.f, 0.f};
#pragma unroll
        for (int kb = 0; kb < 3; ++kb) {
            const int k0 = kb * 32 + quad * 8;
            s16x8 ghi = *(const s16x8*)&gs[(wave * 16 + m) * GROW + k0];
            s16x8 glo = *(const s16x8*)&gs[GA + (wave * 16 + m) * GROW + k0];
#pragma unroll
            for (int nt = 0; nt < 5; ++nt) {
                s16x8 b = *(const s16x8*)&wl[(nt * 16 + m) * WROW + k0];
                a3[nt] = __builtin_amdgcn_mfma_f32_16x16x32_bf16(glo, b, a3[nt], 0, 0, 0);
                a3[nt] = __builtin_amdgcn_mfma_f32_16x16x32_bf16(ghi, b, a3[nt], 0, 0, 0);
            }
        }
        const long base_out = (long)n_ * T_out * 80;
#pragma unroll
        for (int r = 0; r < 4; ++r) {
            int tg = t0 + trow + r;
            if (tg < T_out) {
#pragma unroll
                for (int nt = 0; nt < 5; ++nt) {
                    const int c = nt * 16 + m;
                    out[base_out + (long)tg * 80 + c] = a3[nt][r] + bf1[c];
                }
            }
        }
    }
}

// ============================================================================
__global__ __launch_bounds__(64) void e2_kern(const float* __restrict__ emb,
                                              float* __restrict__ e2o)
{
    int e = blockIdx.x * 64 + threadIdx.x;
    if (e < 512) {
        const float4* p = (const float4*)(emb + e * 80);
        float s = 0.f;
#pragma unroll
        for (int i = 0; i < 20; ++i) {
            float4 v = p[i];
            s += v.x * v.x + v.y * v.y + v.z * v.z + v.w * v.w;
        }
        e2o[e] = s;
    }
}

// ============================================================================
// VQ as register-blocked fp32 GEMM + argmin + fused head (unchanged, known-good).
// ============================================================================
__global__ __launch_bounds__(128) void vq_gemm(
    const float* __restrict__ enc_s,  // (16,2040,80)
    const float* __restrict__ enc_q,  // (16,504,80)
    const float* __restrict__ emb,    // (512,80)
    const float* __restrict__ e2v,    // (512)
    const float* __restrict__ w_lin,  // (2,80)
    const float* __restrict__ b_lin,  // (2)
    float* __restrict__ pred)         // (16,2040,2)
{
    __shared__ __align__(16) float xs[80 * 64];
    __shared__ __align__(16) float es[80 * 64];

    const int tid = threadIdx.x;
    const int tx  = tid & 15;
    const int ty  = tid >> 4;
    const int n   = blockIdx.y;
    const int t0  = blockIdx.x * 64;

#pragma unroll
    for (int mI = 0; mI < 10; ++mI) {
        int u = tid * 10 + mI;
        int tl = u / 20, k4 = u % 20;
        int t = t0 + tl; if (t > 2039) t = 2039;
        float4 v = *(const float4*)(enc_s + ((long)n * 2040 + t) * 80 + k4 * 4);
        xs[(k4 * 4 + 0) * 64 + tl] = v.x;
        xs[(k4 * 4 + 1) * 64 + tl] = v.y;
        xs[(k4 * 4 + 2) * 64 + tl] = v.z;
        xs[(k4 * 4 + 3) * 64 + tl] = v.w;
    }

    float best[8]; int bi[8];
#pragma unroll
    for (int i = 0; i < 8; ++i) { best[i] = 1e30f; bi[i] = 0; }

    for (int e0 = 0; e0 < 512; e0 += 64) {
        __syncthreads();
#pragma unroll
        for (int mI = 0; mI < 10; ++mI) {
            int u = tid * 10 + mI;
            int el = u / 20, k4 = u % 20;
            float4 v = *(const float4*)(emb + (long)(e0 + el) * 80 + k4 * 4);
            es[(k4 * 4 + 0) * 64 + el] = v.x;
            es[(k4 * 4 + 1) * 64 + el] = v.y;
            es[(k4 * 4 + 2) * 64 + el] = v.z;
            es[(k4 * 4 + 3) * 64 + el] = v.w;
        }
        __syncthreads();

        float acc[8][4];
#pragma unroll
        for (int i = 0; i < 8; ++i)
#pragma unroll
            for (int jj = 0; jj < 4; ++jj) acc[i][jj] = 0.f;

#pragma unroll 4
        for (int k = 0; k < 80; ++k) {
            float4 xa = *(const float4*)&xs[k * 64 + ty * 8];
            float4 xb = *(const float4*)&xs[k * 64 + ty * 8 + 4];
            float4 ev = *(const float4*)&es[k * 64 + tx * 4];
            float xv[8] = {xa.x, xa.y, xa.z, xa.w, xb.x, xb.y, xb.z, xb.w};
#pragma unroll
            for (int i = 0; i < 8; ++i)
#pragma unroll
                for (int jj = 0; jj < 4; ++jj)
                    acc[i][jj] = fmaf(xv[i], ((const float*)&ev)[jj], acc[i][jj]);
        }
        float4 e2 = *(const float4*)(e2v + e0 + tx * 4);
#pragma unroll
        for (int i = 0; i < 8; ++i)
#pragma unroll
            for (int jj = 0; jj < 4; ++jj) {
                float s = ((const float*)&e2)[jj] - 2.0f * acc[i][jj];
                if (s < best[i]) { best[i] = s; bi[i] = e0 + tx * 4 + jj; }
            }
    }

    __syncthreads();
    float* rb = es;
    int*   ri = (int*)(es + 1024);
#pragma unroll
    for (int i = 0; i < 8; ++i) {
        rb[(ty * 8 + i) * 16 + tx] = best[i];
        ri[(ty * 8 + i) * 16 + tx] = bi[i];
    }
    __syncthreads();

    if (tid < 64) {
        int t = t0 + tid;
        float b = rb[tid * 16]; int ix = ri[tid * 16];
#pragma unroll
        for (int jj = 1; jj < 16; ++jj) {
            float v = rb[tid * 16 + jj]; int iv = ri[tid * 16 + jj];
            if (v < b || (v == b && iv < ix)) { b = v; ix = iv; }
        }
        if (t < 2040) {
            const float4* ev = (const float4*)(emb + (long)ix * 80);
            const bool hasq = (t < 2016);
            const float4* qv = hasq
                ? (const float4*)(enc_q + ((long)n * 504 + (t % 504)) * 80) : nullptr;
            float p0 = b_lin[0], p1 = b_lin[1];
#pragma unroll
            for (int i = 0; i < 20; ++i) {
                float4 e4 = ev[i];
                float4 q4 = hasq ? qv[i] : make_float4(0.f, 0.f, 0.f, 0.f);
                float4 w0 = *(const float4*)(w_lin + 4 * i);
                float4 w1 = *(const float4*)(w_lin + 80 + 4 * i);
                float sx = e4.x + q4.x, sy = e4.y + q4.y;
                float sz = e4.z + q4.z, sw = e4.w + q4.w;
                p0 = fmaf(sx, w0.x, p0); p1 = fmaf(sx, w1.x, p1);
                p0 = fmaf(sy, w0.y, p0); p1 = fmaf(sy, w1.y, p1);
                p0 = fmaf(sz, w0.z, p0); p1 = fmaf(sz, w1.z, p1);
                p0 = fmaf(sw, w0.w, p0); p1 = fmaf(sw, w1.w, p1);
            }
            long o = ((long)n * 2040 + t) * 2;
            pred[o]     = fast_tanh(p0);
            pred[o + 1] = fast_tanh(p1);
        }
    }
}

// ============================================================================
__global__ __launch_bounds__(256) void max_red(const float* __restrict__ pred,
                                               float* __restrict__ out)
{
    __shared__ float s0[256], s1[256];
    const int n = blockIdx.x, tid = threadIdx.x;
    float m0 = -1e30f, m1 = -1e30f;
    for (int t = tid; t < 2040; t += 256) {
        long o = ((long)n * 2040 + t) * 2;
        m0 = fmaxf(m0, pred[o]);
        m1 = fmaxf(m1, pred[o + 1]);
    }
    s0[tid] = m0; s1[tid] = m1;
    __syncthreads();
    for (int st = 128; st > 0; st >>= 1) {
        if (tid < st) {
            s0[tid] = fmaxf(s0[tid], s0[tid + st]);
            s1[tid] = fmaxf(s1[tid], s1[tid + st]);
        }
        __syncthreads();
    }
    if (tid == 0) { out[n * 2] = s0[0]; out[n * 2 + 1] = s1[0]; }
}

// ============================================================================
extern "C" void kernel_launch(void* const* d_in, const int* in_sizes, int n_in,
                              void* d_out, int out_size, void* d_ws, size_t ws_size,
                              hipStream_t stream)
{
    const float* search = (const float*)d_in[0];
    const float* query  = (const float*)d_in[1];
    const float* w_wide = (const float*)d_in[2];
    const float* b_wide = (const float*)d_in[3];
    const float* w_1x1  = (const float*)d_in[4];
    const float* b_1x1  = (const float*)d_in[5];
    const float* w_f0   = (const float*)d_in[6];
    const float* b_f0   = (const float*)d_in[7];
    const float* w_f1   = (const float*)d_in[8];
    const float* b_f1   = (const float*)d_in[9];
    const float* emb    = (const float*)d_in[10];
    const float* w_lin  = (const float*)d_in[11];
    const float* b_lin  = (const float*)d_in[12];
    float* out = (float*)d_out;
    float* ws  = (float*)d_ws;

    // fp32 buffers (floats):
    float* A  = ws;                 // 5,241,600  (L0s out; later encS; 2040*80*16 fits)
    float* B  = A  + 5241600;       // 2,618,880  (L1s out; later e2)
    float* C  = B  + 2618880;       // 2,618,880  (L2s out; later pred)
    float* QA = C  + 2618880;       // 1,309,440  (L0q out; later encQ)
    float* QB = QA + 1309440;       //   652,800  (L1q out)
    float* QC = QB + 652800;        //   652,800  (L2q out)
    unsigned short* WWp = (unsigned short*)(QC + 652800);
    unsigned short* W1p = WWp + 204800;
    unsigned short* F0p = W1p + 25600;
    unsigned short* F1p = F0p + 6400;

    const int T0s = 4095, T1s = 2046, T2s = 2043, T3s = 2040;
    const int T0q = 1023, T1q = 510,  T2q = 507,  T3q = 504;
    auto nb = [](int T) { return (T + 63) / 64; };
    auto grd = [&](int Ts, int Tq) { return dim3((unsigned)(nb(Ts) + nb(Tq)), NBATCH); };
    const dim3 blk(256);

    pack_w<<<dim3(950), blk, 0, stream>>>(w_wide, w_1x1, w_f0, w_f1,
                                          WWp, W1p, F0p, F1p);

    enc_layer<2, false, false><<<grd(T0s, T0q), blk, 0, stream>>>(
        search, query, WWp, b_wide, W1p, b_1x1,
        nullptr, nullptr, nullptr, nullptr,
        A, QA, 8192, T0s, 2048, T0q, nb(T0s));
    enc_layer<2, true, false><<<grd(T1s, T1q), blk, 0, stream>>>(
        A, QA, WWp + 51200, b_wide + 160, W1p + 6400, b_1x1 + 80,
        nullptr, nullptr, nullptr, nullptr,
        B, QB, T0s, T1s, T0q, T1q, nb(T1s));
    enc_layer<1, true, false><<<grd(T2s, T2q), blk, 0, stream>>>(
        B, QB, WWp + 102400, b_wide + 320, W1p + 12800, b_1x1 + 160,
        nullptr, nullptr, nullptr, nullptr,
        C, QC, T1s, T2s, T1q, T2q, nb(T2s));
    enc_layer<1, true, true><<<grd(T3s, T3q), blk, 0, stream>>>(
        C, QC, WWp + 153600, b_wide + 480, W1p + 19200, b_1x1 + 240,
        F0p, b_f0, F1p, b_f1,
        A, QA, T2s, T3s, T2q, T3q, nb(T3s));

    e2_kern<<<dim3(8), dim3(64), 0, stream>>>(emb, B);
    vq_gemm<<<dim3(32, NBATCH), dim3(128), 0, stream>>>(A, QA, emb, B, w_lin, b_lin, C);
    max_red<<<dim3(NBATCH), blk, 0, stream>>>(C, out);
}

// Round 5
// 319.558 us; speedup vs baseline: 4.2327x; 1.1080x over previous
//
#include <hip/hip_runtime.h>
#include <math.h>

// ---------------------------------------------------------------------------
// AudioFinder, MFMA v2.
// Encoder: bf16 MFMA (no hi/lo split), W pre-packed k'-major (k'=j*80+ic),
// wave owns MT m-tiles (B-frag reuse), x staged once/block, W chunks
// register-prefetched. VQ: bf16 MFMA GEMM + argmin + fp32 head.
// ---------------------------------------------------------------------------

#define NBATCH 16

typedef __attribute__((ext_vector_type(8))) short s16x8;
typedef __attribute__((ext_vector_type(4))) float f32x4;

__device__ __forceinline__ float fast_sigmoid(float x){ return 1.0f/(1.0f+__expf(-x)); }
__device__ __forceinline__ float fast_tanh(float x){ return 2.0f/(1.0f+__expf(-2.0f*x))-1.0f; }
__device__ __forceinline__ unsigned short f2bf(float f){
    unsigned int u = __float_as_uint(f);
    return (unsigned short)((u + 0x7FFFu + ((u >> 16) & 1u)) >> 16);
}

// ============================================================================
// One-time packs: WW (4,160,320) k'-major bf16; W1/F0/F1 bf16; EMB bf16; e2.
// ============================================================================
__global__ __launch_bounds__(256) void pack_all(
    const float* __restrict__ w_wide, const float* __restrict__ w_1x1,
    const float* __restrict__ wf0,    const float* __restrict__ wf1,
    const float* __restrict__ emb,
    unsigned short* __restrict__ WW, unsigned short* __restrict__ W1,
    unsigned short* __restrict__ F0, unsigned short* __restrict__ F1,
    unsigned short* __restrict__ EM, float* __restrict__ e2o)
{
    int i = blockIdx.x * 256 + threadIdx.x;
    if (i < 204800) {
        int l = i / 51200, r = i % 51200, oc = r / 320, k = r % 320;
        int j = k / 80, ic = k % 80;
        WW[i] = f2bf(w_wide[l * 51200 + oc * 320 + ic * 4 + j]);
    } else if (i < 230400) {
        W1[i - 204800] = f2bf(w_1x1[i - 204800]);
    } else if (i < 236800) {
        F0[i - 230400] = f2bf(wf0[i - 230400]);
    } else if (i < 243200) {
        F1[i - 236800] = f2bf(wf1[i - 236800]);
    } else if (i < 284160) {
        EM[i - 243200] = f2bf(emb[i - 243200]);
    } else if (i < 284672) {
        int e = i - 284160;
        float s = 0.f;
        for (int k = 0; k < 80; ++k) { float v = emb[e * 80 + k]; s = fmaf(v, v, s); }
        e2o[e] = s;
    }
}

// ============================================================================
// Fused encoder layer. 256 thr / 4 waves; wave owns MT m-tiles (16t each).
// Block tile = 4*MT*16 t x 160 oc. MT=2 (S=2) / 3 (S=1).
// x staged once (bf16, parity-split rows for S=2); W in CHK-k chunks,
// register-prefetched; 1x1 (+f0/f1 if FINAL) via MFMA, K padded to 96.
// Frag layouts (verified m89/m120): A/B [m|n=lane&15][k=quad*8+j];
// D col=lane&15, row=quad*4+reg.
// ============================================================================
template<int S, bool HAS_RES, bool FINAL>
__global__ __launch_bounds__(256, 2) void enc_layer(
    const float* __restrict__ xS, const float* __restrict__ xQ,
    const unsigned short* __restrict__ ww,  const float* __restrict__ wb,
    const unsigned short* __restrict__ w1p, const float* __restrict__ b1,
    const unsigned short* __restrict__ f0p, const float* __restrict__ bf0,
    const unsigned short* __restrict__ f1p, const float* __restrict__ bf1,
    float* __restrict__ outS, float* __restrict__ outQ,
    int TinS, int ToutS, int TinQ, int ToutQ, int nbS)
{
    constexpr int MT   = (S == 2) ? 2 : 3;
    constexpr int TB   = 4 * MT * 16;            // 128 / 192
    constexpr int P    = (TB - 1) * S + 4;       // 258 / 195
    constexpr int HALF = (S == 2) ? 130 : 196;
    constexpr int NPAR = (S == 2) ? 2 : 1;
    constexpr int XS_SH = NPAR * HALF * 88;      // 22880 / 17248
    constexpr int GS_SH = TB * 104;              // 13312 / 19968
    constexpr int R1   = (XS_SH > GS_SH) ? XS_SH : GS_SH;
    constexpr int CHK  = (S == 2) ? 32 : 64;
    constexpr int NCHK = 320 / CHK;
    constexpr int KPC  = CHK / 32;
    constexpr int WROW = (S == 2) ? 40 : 72;
    constexpr int W1B  = (R1 - GS_SH >= 80 * 104) ? GS_SH : R1;  // 1x1 W region
    __shared__ unsigned short smem[R1 + 160 * WROW];
    unsigned short* xs  = smem;
    unsigned short* gs  = smem;
    unsigned short* wl  = smem + R1;
    unsigned short* w1l = smem + W1B;

    const int tid  = threadIdx.x;
    const int wave = tid >> 6;
    const int lane = tid & 63;
    const int m    = lane & 15;
    const int quad = lane >> 4;
    const int n_   = blockIdx.y;
    const int wbase = wave * (MT * 16);

    const float* x; float* out; int T_in, T_out, bx;
    if ((int)blockIdx.x < nbS) { x = xS; out = outS; T_in = TinS; T_out = ToutS; bx = blockIdx.x; }
    else                       { x = xQ; out = outQ; T_in = TinQ; T_out = ToutQ; bx = blockIdx.x - nbS; }
    const int t0 = bx * TB;
    const long base_in = (long)n_ * T_in * 80;

    // ---- stage x tile once (bf16) ----
    for (int u = tid; u < P * 20; u += 256) {
        int pos = u / 20, c4 = u % 20;
        int tp = t0 * S + pos; if (tp > T_in - 1) tp = T_in - 1;
        float4 v = *(const float4*)(x + base_in + (long)tp * 80 + c4 * 4);
        int row, par;
        if (S == 2) { row = pos >> 1; par = pos & 1; } else { row = pos; par = 0; }
        int o = (par * HALF + row) * 88 + c4 * 4;
        unsigned int s0 = (unsigned int)f2bf(v.x) | ((unsigned int)f2bf(v.y) << 16);
        unsigned int s1 = (unsigned int)f2bf(v.z) | ((unsigned int)f2bf(v.w) << 16);
        *(uint2*)&xs[o] = make_uint2(s0, s1);
    }

    // ---- wide conv with register-prefetched W chunks ----
    constexpr int NSEG = CHK / 8;
    constexpr int WU   = 160 * NSEG;
    constexpr int WI   = (WU + 255) / 256;
    uint4 wreg[WI];
    auto ldW = [&](int c) {
#pragma unroll
        for (int i = 0; i < WI; ++i) {
            int u = tid + 256 * i;
            if (u < WU) {
                int row = u / NSEG, seg = u % NSEG;
                wreg[i] = *(const uint4*)(ww + row * 320 + c * CHK + seg * 8);
            }
        }
    };
    auto stW = [&]() {
#pragma unroll
        for (int i = 0; i < WI; ++i) {
            int u = tid + 256 * i;
            if (u < WU) {
                int row = u / NSEG, seg = u % NSEG;
                *(uint4*)&wl[row * WROW + seg * 8] = wreg[i];
            }
        }
    };

    f32x4 acc[MT][10];
#pragma unroll
    for (int mt = 0; mt < MT; ++mt)
#pragma unroll
        for (int nt = 0; nt < 10; ++nt) acc[mt][nt] = (f32x4){0.f, 0.f, 0.f, 0.f};

    ldW(0);
    for (int c = 0; c < NCHK; ++c) {
        __syncthreads();
        stW();
        __syncthreads();
        if (c + 1 < NCHK) ldW(c + 1);
#pragma unroll
        for (int kc = 0; kc < KPC; ++kc) {
            const int kk = c * KPC + kc;
            const int kq = kk * 32 + quad * 8;
            const int j = kq / 80, ic0 = kq % 80;
            s16x8 a[MT];
#pragma unroll
            for (int mt = 0; mt < MT; ++mt) {
                int t_l = wbase + mt * 16 + m;
                int xo;
                if (S == 2) xo = ((j & 1) * HALF + t_l + (j >> 1)) * 88 + ic0;
                else        xo = (t_l + j) * 88 + ic0;
                a[mt] = *(const s16x8*)&xs[xo];
            }
#pragma unroll
            for (int nt = 0; nt < 10; ++nt) {
                s16x8 b = *(const s16x8*)&wl[(nt * 16 + m) * WROW + kc * 32 + quad * 8];
#pragma unroll
                for (int mt = 0; mt < MT; ++mt)
                    acc[mt][nt] = __builtin_amdgcn_mfma_f32_16x16x32_bf16(a[mt], b, acc[mt][nt], 0, 0, 0);
            }
        }
    }

    // ---- gate -> gs (bf16), zero K-pad; stage w1 ----
    __syncthreads();   // all waves done with xs/wl
    const uint4 z4 = make_uint4(0u, 0u, 0u, 0u);
#pragma unroll
    for (int mt = 0; mt < MT; ++mt)
#pragma unroll
        for (int nt = 0; nt < 5; ++nt) {
            const int cc = nt * 16 + m;
            const float ba = wb[cc], bg = wb[80 + cc];
#pragma unroll
            for (int r = 0; r < 4; ++r) {
                float a = acc[mt][nt][r] + ba;
                float g = acc[mt][nt + 5][r] + bg;
                gs[(wbase + mt * 16 + quad * 4 + r) * 104 + cc] =
                    f2bf(fast_tanh(a) * fast_sigmoid(g));
            }
        }
    for (int u = tid; u < TB * 2; u += 256)
        *(uint4*)&gs[(u >> 1) * 104 + 80 + (u & 1) * 8] = z4;
    auto stage80 = [&](const unsigned short* Wp) {
        for (int u = tid; u < 960; u += 256) {
            int row = u / 12, seg = u % 12;
            uint4 v = z4;
            if (seg < 10) v = *(const uint4*)(Wp + row * 80 + seg * 8);
            *(uint4*)&w1l[row * 104 + seg * 8] = v;
        }
    };
    stage80(w1p);
    __syncthreads();

    auto mm80 = [&](f32x4 (&o)[MT][5]) {
#pragma unroll
        for (int mt = 0; mt < MT; ++mt)
#pragma unroll
            for (int nt = 0; nt < 5; ++nt) o[mt][nt] = (f32x4){0.f, 0.f, 0.f, 0.f};
#pragma unroll
        for (int kb = 0; kb < 3; ++kb) {
            const int k0 = kb * 32 + quad * 8;
            s16x8 ag[MT];
#pragma unroll
            for (int mt = 0; mt < MT; ++mt)
                ag[mt] = *(const s16x8*)&gs[(wbase + mt * 16 + m) * 104 + k0];
#pragma unroll
            for (int nt = 0; nt < 5; ++nt) {
                s16x8 b = *(const s16x8*)&w1l[(nt * 16 + m) * 104 + k0];
#pragma unroll
                for (int mt = 0; mt < MT; ++mt)
                    o[mt][nt] = __builtin_amdgcn_mfma_f32_16x16x32_bf16(ag[mt], b, o[mt][nt], 0, 0, 0);
            }
        }
    };

    f32x4 a1[MT][5];
    mm80(a1);

    const long base_out = (long)n_ * T_out * 80;
    if (!FINAL) {
#pragma unroll
        for (int mt = 0; mt < MT; ++mt)
#pragma unroll
            for (int r = 0; r < 4; ++r) {
                int tg = t0 + wbase + mt * 16 + quad * 4 + r;
                if (tg < T_out) {
#pragma unroll
                    for (int nt = 0; nt < 5; ++nt) {
                        const int cc = nt * 16 + m;
                        float v = a1[mt][nt][r] + b1[cc];
                        if (HAS_RES)
                            v += x[base_in + (long)(3 + (long)tg * S) * 80 + cc];
                        out[base_out + (long)tg * 80 + cc] = v;
                    }
                }
            }
    } else {
        __syncthreads();   // everyone done reading gs/w1l
        // x3 = a1 + b1 + residual -> gs (pads stay zero)
#pragma unroll
        for (int mt = 0; mt < MT; ++mt)
#pragma unroll
            for (int r = 0; r < 4; ++r) {
                int tg = t0 + wbase + mt * 16 + quad * 4 + r;
                int tc = (tg < T_out) ? tg : (T_out - 1);
#pragma unroll
                for (int nt = 0; nt < 5; ++nt) {
                    const int cc = nt * 16 + m;
                    float v = a1[mt][nt][r] + b1[cc];
                    if (HAS_RES)
                        v += x[base_in + (long)(3 + (long)tc * S) * 80 + cc];
                    gs[(wbase + mt * 16 + quad * 4 + r) * 104 + cc] = f2bf(v);
                }
            }
        stage80(f0p);
        __syncthreads();
        f32x4 a2[MT][5];
        mm80(a2);
        __syncthreads();
#pragma unroll
        for (int mt = 0; mt < MT; ++mt)
#pragma unroll
            for (int nt = 0; nt < 5; ++nt)
#pragma unroll
                for (int r = 0; r < 4; ++r)
                    gs[(wbase + mt * 16 + quad * 4 + r) * 104 + nt * 16 + m] =
                        f2bf(fmaxf(a2[mt][nt][r] + bf0[nt * 16 + m], 0.f));
        stage80(f1p);
        __syncthreads();
        f32x4 a3[MT][5];
        mm80(a3);
#pragma unroll
        for (int mt = 0; mt < MT; ++mt)
#pragma unroll
            for (int r = 0; r < 4; ++r) {
                int tg = t0 + wbase + mt * 16 + quad * 4 + r;
                if (tg < T_out) {
#pragma unroll
                    for (int nt = 0; nt < 5; ++nt)
                        out[base_out + (long)tg * 80 + nt * 16 + m] =
                            a3[mt][nt][r] + bf1[nt * 16 + m];
                }
            }
    }
}

// ============================================================================
// VQ via bf16 MFMA: block 256 thr / 4 waves, tile 64t; e chunked 4x128
// (8 n-tiles). A-frags register-resident; per-lane argmin over D-layout,
// LDS lex-reduce across 16 cols, fused fp32 head + tanh.
// ============================================================================
__global__ __launch_bounds__(256, 2) void vq_mfma(
    const float* __restrict__ enc_s,          // (16,2040,80) fp32
    const float* __restrict__ enc_q,          // (16,504,80)  fp32
    const unsigned short* __restrict__ embp,  // (512,80) bf16
    const float* __restrict__ emb,            // (512,80) fp32
    const float* __restrict__ e2v,            // (512)
    const float* __restrict__ w_lin, const float* __restrict__ b_lin,
    float* __restrict__ pred)                 // (16,2040,2)
{
    __shared__ unsigned short xs[64 * 104];    // [t][k] bf16, pad-zeroed 80..95
    __shared__ unsigned short es[128 * 104];   // [e][k] bf16 (chunk), aliased later
    const uint4 z4 = make_uint4(0u, 0u, 0u, 0u);

    const int tid  = threadIdx.x;
    const int wave = tid >> 6;
    const int lane = tid & 63;
    const int m    = lane & 15;
    const int quad = lane >> 4;
    const int n    = blockIdx.y;
    const int t0   = blockIdx.x * 64;

    for (int u = tid; u < 64 * 20; u += 256) {
        int row = u / 20, c4 = u % 20;
        int t = t0 + row; if (t > 2039) t = 2039;
        float4 v = *(const float4*)(enc_s + ((long)n * 2040 + t) * 80 + c4 * 4);
        unsigned int s0 = (unsigned int)f2bf(v.x) | ((unsigned int)f2bf(v.y) << 16);
        unsigned int s1 = (unsigned int)f2bf(v.z) | ((unsigned int)f2bf(v.w) << 16);
        *(uint2*)&xs[row * 104 + c4 * 4] = make_uint2(s0, s1);
    }
    for (int u = tid; u < 128; u += 256)
        *(uint4*)&xs[(u >> 1) * 104 + 80 + (u & 1) * 8] = z4;
    __syncthreads();

    s16x8 af[3];
#pragma unroll
    for (int kb = 0; kb < 3; ++kb)
        af[kb] = *(const s16x8*)&xs[(wave * 16 + m) * 104 + kb * 32 + quad * 8];

    float best[4]; int bi[4];
#pragma unroll
    for (int r = 0; r < 4; ++r) { best[r] = 1e30f; bi[r] = 0; }

    for (int ch = 0; ch < 4; ++ch) {
        const int c0 = ch * 128;
        __syncthreads();
        for (int u = tid; u < 128 * 12; u += 256) {
            int el = u / 12, seg = u % 12;
            uint4 v = z4;
            if (seg < 10) v = *(const uint4*)(embp + (long)(c0 + el) * 80 + seg * 8);
            *(uint4*)&es[el * 104 + seg * 8] = v;
        }
        __syncthreads();

        f32x4 acc[8];
#pragma unroll
        for (int nt = 0; nt < 8; ++nt) acc[nt] = (f32x4){0.f, 0.f, 0.f, 0.f};
#pragma unroll
        for (int kb = 0; kb < 3; ++kb) {
            const int k0 = kb * 32 + quad * 8;
#pragma unroll
            for (int nt = 0; nt < 8; ++nt) {
                s16x8 b = *(const s16x8*)&es[(nt * 16 + m) * 104 + k0];
                acc[nt] = __builtin_amdgcn_mfma_f32_16x16x32_bf16(af[kb], b, acc[nt], 0, 0, 0);
            }
        }
#pragma unroll
        for (int nt = 0; nt < 8; ++nt) {
            const int e = c0 + nt * 16 + m;
            const float e2x = e2v[e];
#pragma unroll
            for (int r = 0; r < 4; ++r) {
                float s = fmaf(-2.0f, acc[nt][r], e2x);
                if (s < best[r]) { best[r] = s; bi[r] = e; }
            }
        }
    }

    // cross-col lex-reduce via LDS (alias es)
    __syncthreads();
    float* rb = (float*)es;
    int*   ri = (int*)es + 1088;
#pragma unroll
    for (int r = 0; r < 4; ++r) {
        int tl = wave * 16 + quad * 4 + r;
        rb[tl * 17 + m] = best[r];
        ri[tl * 17 + m] = bi[r];
    }
    __syncthreads();

    if (tid < 64) {
        const int t = t0 + tid;
        float b = rb[tid * 17]; int ix = ri[tid * 17];
#pragma unroll
        for (int j = 1; j < 16; ++j) {
            float v = rb[tid * 17 + j]; int iv = ri[tid * 17 + j];
            if (v < b || (v == b && iv < ix)) { b = v; ix = iv; }
        }
        if (t < 2040) {
            const float4* ev = (const float4*)(emb + (long)ix * 80);
            const bool hasq = (t < 2016);
            const float4* qv = hasq
                ? (const float4*)(enc_q + ((long)n * 504 + (t % 504)) * 80) : nullptr;
            float p0 = b_lin[0], p1 = b_lin[1];
#pragma unroll
            for (int i = 0; i < 20; ++i) {
                float4 e4 = ev[i];
                float4 q4 = hasq ? qv[i] : make_float4(0.f, 0.f, 0.f, 0.f);
                float4 w0 = *(const float4*)(w_lin + 4 * i);
                float4 w1 = *(const float4*)(w_lin + 80 + 4 * i);
                float sx = e4.x + q4.x, sy = e4.y + q4.y;
                float sz = e4.z + q4.z, sw = e4.w + q4.w;
                p0 = fmaf(sx, w0.x, p0); p1 = fmaf(sx, w1.x, p1);
                p0 = fmaf(sy, w0.y, p0); p1 = fmaf(sy, w1.y, p1);
                p0 = fmaf(sz, w0.z, p0); p1 = fmaf(sz, w1.z, p1);
                p0 = fmaf(sw, w0.w, p0); p1 = fmaf(sw, w1.w, p1);
            }
            long o = ((long)n * 2040 + t) * 2;
            pred[o]     = fast_tanh(p0);
            pred[o + 1] = fast_tanh(p1);
        }
    }
}

// ============================================================================
__global__ __launch_bounds__(256) void max_red(const float* __restrict__ pred,
                                               float* __restrict__ out)
{
    __shared__ float s0[256], s1[256];
    const int n = blockIdx.x, tid = threadIdx.x;
    float m0 = -1e30f, m1 = -1e30f;
    for (int t = tid; t < 2040; t += 256) {
        long o = ((long)n * 2040 + t) * 2;
        m0 = fmaxf(m0, pred[o]);
        m1 = fmaxf(m1, pred[o + 1]);
    }
    s0[tid] = m0; s1[tid] = m1;
    __syncthreads();
    for (int st = 128; st > 0; st >>= 1) {
        if (tid < st) {
            s0[tid] = fmaxf(s0[tid], s0[tid + st]);
            s1[tid] = fmaxf(s1[tid], s1[tid + st]);
        }
        __syncthreads();
    }
    if (tid == 0) { out[n * 2] = s0[0]; out[n * 2 + 1] = s1[0]; }
}

// ============================================================================
extern "C" void kernel_launch(void* const* d_in, const int* in_sizes, int n_in,
                              void* d_out, int out_size, void* d_ws, size_t ws_size,
                              hipStream_t stream)
{
    const float* search = (const float*)d_in[0];
    const float* query  = (const float*)d_in[1];
    const float* w_wide = (const float*)d_in[2];
    const float* b_wide = (const float*)d_in[3];
    const float* w_1x1  = (const float*)d_in[4];
    const float* b_1x1  = (const float*)d_in[5];
    const float* w_f0   = (const float*)d_in[6];
    const float* b_f0   = (const float*)d_in[7];
    const float* w_f1   = (const float*)d_in[8];
    const float* b_f1   = (const float*)d_in[9];
    const float* emb    = (const float*)d_in[10];
    const float* w_lin  = (const float*)d_in[11];
    const float* b_lin  = (const float*)d_in[12];
    float* out = (float*)d_out;
    float* ws  = (float*)d_ws;

    // fp32 flow: L0: in->A/QA; L1: A->B/QB; L2: B->C/QC; L3: C->B(encS)/QB(encQ);
    // vq: pred->C.
    float* A  = ws;                 // 5,241,600
    float* B  = A  + 5241600;       // 2,618,880
    float* C  = B  + 2618880;       // 2,618,880
    float* QA = C  + 2618880;       // 1,309,440
    float* QB = QA + 1309440;       //   652,800
    float* QC = QB + 652800;        //   652,800
    unsigned short* WWp = (unsigned short*)(QC + 652800);
    unsigned short* W1p = WWp + 204800;
    unsigned short* F0p = W1p + 25600;
    unsigned short* F1p = F0p + 6400;
    unsigned short* EMp = F1p + 6400;          // 40960
    float* e2b = (float*)(EMp + 40960);        // 512

    const dim3 blk(256);
    auto nb = [](int T, int TBv) { return (T + TBv - 1) / TBv; };

    pack_all<<<dim3(1112), blk, 0, stream>>>(w_wide, w_1x1, w_f0, w_f1, emb,
                                             WWp, W1p, F0p, F1p, EMp, e2b);

    // L0: S=2, TB=128
    enc_layer<2, false, false><<<dim3(nb(4095,128) + nb(1023,128), NBATCH), blk, 0, stream>>>(
        search, query, WWp, b_wide, W1p, b_1x1, nullptr, nullptr, nullptr, nullptr,
        A, QA, 8192, 4095, 2048, 1023, nb(4095,128));
    // L1: S=2
    enc_layer<2, true, false><<<dim3(nb(2046,128) + nb(510,128), NBATCH), blk, 0, stream>>>(
        A, QA, WWp + 51200, b_wide + 160, W1p + 6400, b_1x1 + 80,
        nullptr, nullptr, nullptr, nullptr,
        B, QB, 4095, 2046, 1023, 510, nb(2046,128));
    // L2: S=1, TB=192
    enc_layer<1, true, false><<<dim3(nb(2043,192) + nb(507,192), NBATCH), blk, 0, stream>>>(
        B, QB, WWp + 102400, b_wide + 320, W1p + 12800, b_1x1 + 160,
        nullptr, nullptr, nullptr, nullptr,
        C, QC, 2046, 2043, 510, 507, nb(2043,192));
    // L3: S=1, FINAL -> encS in B, encQ in QB
    enc_layer<1, true, true><<<dim3(nb(2040,192) + nb(504,192), NBATCH), blk, 0, stream>>>(
        C, QC, WWp + 153600, b_wide + 480, W1p + 19200, b_1x1 + 240,
        F0p, b_f0, F1p, b_f1,
        B, QB, 2043, 2040, 507, 504, nb(2040,192));

    vq_mfma<<<dim3(32, NBATCH), blk, 0, stream>>>(B, QB, EMp, emb, e2b,
                                                  w_lin, b_lin, C);
    max_red<<<dim3(NBATCH), blk, 0, stream>>>(C, out);
}

// Round 6
// 234.522 us; speedup vs baseline: 5.7675x; 1.3626x over previous
//
#include <hip/hip_runtime.h>
#include <math.h>

// ---------------------------------------------------------------------------
// AudioFinder, MFMA v3 — barrier-free K-loop.
// Block = 320 thr / 5 waves; tile 64t x 160oc; wave w owns n-tiles (w, w+5)
// = the GLU (a,g) pair. W streams from global into registers (L2-resident,
// no LDS, no staging barriers). LDS holds only the x tile (and g for 1x1).
// All weights pre-packed bf16 (wide: k'-major, k'=j*80+ic; 1x1: K padded 96).
// ---------------------------------------------------------------------------

#define NBATCH 16

typedef __attribute__((ext_vector_type(8))) short s16x8;
typedef __attribute__((ext_vector_type(4))) float f32x4;

__device__ __forceinline__ float fast_sigmoid(float x){ return 1.0f/(1.0f+__expf(-x)); }
__device__ __forceinline__ float fast_tanh(float x){ return 2.0f/(1.0f+__expf(-2.0f*x))-1.0f; }
__device__ __forceinline__ unsigned short f2bf(float f){
    unsigned int u = __float_as_uint(f);
    return (unsigned short)((u + 0x7FFFu + ((u >> 16) & 1u)) >> 16);
}

// ============================================================================
// One-time packs: WW (4,160,320) k'-major; W1/F0/F1 (·,80,96) zero-padded;
// EMB bf16; e2.
// ============================================================================
__global__ __launch_bounds__(256) void pack_all(
    const float* __restrict__ w_wide, const float* __restrict__ w_1x1,
    const float* __restrict__ wf0,    const float* __restrict__ wf1,
    const float* __restrict__ emb,
    unsigned short* __restrict__ WW, unsigned short* __restrict__ W1,
    unsigned short* __restrict__ F0, unsigned short* __restrict__ F1,
    unsigned short* __restrict__ EM, float* __restrict__ e2o)
{
    int i = blockIdx.x * 256 + threadIdx.x;
    if (i < 204800) {
        int l = i / 51200, r = i % 51200, oc = r / 320, k = r % 320;
        int j = k / 80, ic = k % 80;
        WW[i] = f2bf(w_wide[l * 51200 + oc * 320 + ic * 4 + j]);
    } else if (i < 235520) {
        int idx = i - 204800, l = idx / 7680, r = idx % 7680, oc = r / 96, k = r % 96;
        W1[idx] = (k < 80) ? f2bf(w_1x1[l * 6400 + oc * 80 + k]) : (unsigned short)0;
    } else if (i < 243200) {
        int idx = i - 235520, oc = idx / 96, k = idx % 96;
        F0[idx] = (k < 80) ? f2bf(wf0[oc * 80 + k]) : (unsigned short)0;
    } else if (i < 250880) {
        int idx = i - 243200, oc = idx / 96, k = idx % 96;
        F1[idx] = (k < 80) ? f2bf(wf1[oc * 80 + k]) : (unsigned short)0;
    } else if (i < 291840) {
        EM[i - 250880] = f2bf(emb[i - 250880]);
    } else if (i < 292352) {
        int e = i - 291840;
        float s = 0.f;
        for (int k = 0; k < 80; ++k) { float v = emb[e * 80 + k]; s = fmaf(v, v, s); }
        e2o[e] = s;
    }
}

// ============================================================================
// Fused encoder layer v3.
// Frag layouts (verified m89/m120): A/B lane: [m|n=lane&15][k=quad*8+j];
// D: col=lane&15 (n), row=quad*4+reg (m).
// ============================================================================
template<int S, bool HAS_RES, bool FINAL>
__global__ __launch_bounds__(320, 3) void enc_layer(
    const float* __restrict__ xS, const float* __restrict__ xQ,
    const unsigned short* __restrict__ ww,  const float* __restrict__ wb,
    const unsigned short* __restrict__ w1p, const float* __restrict__ b1,
    const unsigned short* __restrict__ f0p, const float* __restrict__ bf0,
    const unsigned short* __restrict__ f1p, const float* __restrict__ bf1,
    float* __restrict__ outS, float* __restrict__ outQ,
    int TinS, int ToutS, int TinQ, int ToutQ, int nbS)
{
    constexpr int P    = 63 * S + 4;                 // 130 / 67
    constexpr int HALF = (S == 2) ? 65 : 67;         // rows per parity
    constexpr int NPAR = (S == 2) ? 2 : 1;
    constexpr int XS_SH = NPAR * HALF * 88;          // 11440 / 5896 shorts
    constexpr int GS_SH = 64 * 104;                  // 6656
    constexpr int R1   = (XS_SH > GS_SH) ? XS_SH : GS_SH;
    __shared__ unsigned short smem[R1];
    unsigned short* xs = smem;
    unsigned short* gs = smem;                       // aliased after K-loop

    const int tid  = threadIdx.x;
    const int wave = tid >> 6;                       // 0..4 = n-pair
    const int lane = tid & 63;
    const int m    = lane & 15;
    const int quad = lane >> 4;
    const int n_   = blockIdx.y;

    const float* x; float* out; int T_in, T_out, bx;
    if ((int)blockIdx.x < nbS) { x = xS; out = outS; T_in = TinS; T_out = ToutS; bx = blockIdx.x; }
    else                       { x = xQ; out = outQ; T_in = TinQ; T_out = ToutQ; bx = blockIdx.x - nbS; }
    const int t0 = bx * 64;
    const long base_in = (long)n_ * T_in * 80;

    // ---- stage x tile (fp32 -> bf16, parity rows for S=2) ----
    for (int u = tid; u < P * 20; u += 320) {
        int pos = u / 20, c4 = u % 20;
        int tp = t0 * S + pos; if (tp > T_in - 1) tp = T_in - 1;
        float4 v = *(const float4*)(x + base_in + (long)tp * 80 + c4 * 4);
        int row = (S == 2) ? (pos >> 1) : pos;
        int par = (S == 2) ? (pos & 1) : 0;
        int o = (par * HALF + row) * 88 + c4 * 4;
        unsigned int s0 = (unsigned int)f2bf(v.x) | ((unsigned int)f2bf(v.y) << 16);
        unsigned int s1 = (unsigned int)f2bf(v.z) | ((unsigned int)f2bf(v.w) << 16);
        *(uint2*)&xs[o] = make_uint2(s0, s1);
    }

    // ---- B-frag global pointers (registers, depth-2 pipeline) ----
    const int quad8 = quad * 8;
    const unsigned short* wa_base = ww + (long)(wave * 16 + m) * 320 + quad8;
    const unsigned short* wg_base = ww + (long)((wave + 5) * 16 + m) * 320 + quad8;
    auto ldB = [&](const unsigned short* b, int kk) { return *(const s16x8*)(b + kk * 32); };

    s16x8 baP[3], bgP[3];
    baP[0] = ldB(wa_base, 0); bgP[0] = ldB(wg_base, 0);
    baP[1] = ldB(wa_base, 1); bgP[1] = ldB(wg_base, 1);

    f32x4 acc_a[4], acc_g[4];
#pragma unroll
    for (int mt = 0; mt < 4; ++mt) {
        acc_a[mt] = (f32x4){0.f, 0.f, 0.f, 0.f};
        acc_g[mt] = (f32x4){0.f, 0.f, 0.f, 0.f};
    }

    __syncthreads();   // xs ready

    // ---- wide conv K-loop: NO barriers ----
#pragma unroll
    for (int kk = 0; kk < 10; ++kk) {
        if (kk + 2 < 10) {
            baP[(kk + 2) % 3] = ldB(wa_base, kk + 2);
            bgP[(kk + 2) % 3] = ldB(wg_base, kk + 2);
        }
        const int kq = kk * 32 + quad8;
        const int j  = (kq >= 240) ? 3 : ((kq >= 160) ? 2 : ((kq >= 80) ? 1 : 0));
        const int ic0 = kq - j * 80;
        int xb;
        if (S == 2) xb = ((j & 1) * HALF + (j >> 1)) * 88 + ic0;
        else        xb = j * 88 + ic0;
        s16x8 a[4];
#pragma unroll
        for (int mt = 0; mt < 4; ++mt)
            a[mt] = *(const s16x8*)&xs[xb + (mt * 16 + m) * 88];
        s16x8 ba = baP[kk % 3], bg = bgP[kk % 3];
#pragma unroll
        for (int mt = 0; mt < 4; ++mt) {
            acc_a[mt] = __builtin_amdgcn_mfma_f32_16x16x32_bf16(a[mt], ba, acc_a[mt], 0, 0, 0);
            acc_g[mt] = __builtin_amdgcn_mfma_f32_16x16x32_bf16(a[mt], bg, acc_g[mt], 0, 0, 0);
        }
    }

    // ---- gate -> gs (bf16) ----
    __syncthreads();   // all waves done reading xs (gs aliases)
    const float ba_b = wb[wave * 16 + m];
    const float bg_b = wb[80 + wave * 16 + m];
#pragma unroll
    for (int mt = 0; mt < 4; ++mt)
#pragma unroll
        for (int r = 0; r < 4; ++r) {
            float av = acc_a[mt][r] + ba_b;
            float gv = acc_g[mt][r] + bg_b;
            gs[(mt * 16 + quad * 4 + r) * 104 + wave * 16 + m] =
                f2bf(fast_tanh(av) * fast_sigmoid(gv));
        }
    const uint4 z4 = make_uint4(0u, 0u, 0u, 0u);
    for (int u = tid; u < 128; u += 320)
        *(uint4*)&gs[(u >> 1) * 104 + 80 + (u & 1) * 8] = z4;
    __syncthreads();

    // ---- 1x1 (K=96, B zero-padded at pack time) ----
    auto mm96 = [&](const unsigned short* Wp, f32x4 (&o)[4]) {
        const unsigned short* wb1 = Wp + (long)(wave * 16 + m) * 96 + quad8;
        s16x8 b0 = *(const s16x8*)(wb1);
        s16x8 b1f = *(const s16x8*)(wb1 + 32);
        s16x8 b2 = *(const s16x8*)(wb1 + 64);
#pragma unroll
        for (int mt = 0; mt < 4; ++mt) o[mt] = (f32x4){0.f, 0.f, 0.f, 0.f};
#pragma unroll
        for (int kb = 0; kb < 3; ++kb) {
            s16x8 b = (kb == 0) ? b0 : ((kb == 1) ? b1f : b2);
#pragma unroll
            for (int mt = 0; mt < 4; ++mt) {
                s16x8 ag = *(const s16x8*)&gs[(mt * 16 + m) * 104 + kb * 32 + quad8];
                o[mt] = __builtin_amdgcn_mfma_f32_16x16x32_bf16(ag, b, o[mt], 0, 0, 0);
            }
        }
    };

    f32x4 a1[4];
    mm96(w1p, a1);

    const long base_out = (long)n_ * T_out * 80;
    const int c = wave * 16 + m;
    if (!FINAL) {
        const float b1c = b1[c];
#pragma unroll
        for (int mt = 0; mt < 4; ++mt)
#pragma unroll
            for (int r = 0; r < 4; ++r) {
                int tg = t0 + mt * 16 + quad * 4 + r;
                if (tg < T_out) {
                    float v = a1[mt][r] + b1c;
                    if (HAS_RES)
                        v += x[base_in + (long)(3 + (long)tg * S) * 80 + c];
                    out[base_out + (long)tg * 80 + c] = v;
                }
            }
    } else {
        const float b1c = b1[c];
        float x3[4][4];
#pragma unroll
        for (int mt = 0; mt < 4; ++mt)
#pragma unroll
            for (int r = 0; r < 4; ++r) {
                int tg = t0 + mt * 16 + quad * 4 + r;
                int tc = (tg < T_out) ? tg : (T_out - 1);
                float v = a1[mt][r] + b1c;
                if (HAS_RES)
                    v += x[base_in + (long)(3 + (long)tc * S) * 80 + c];
                x3[mt][r] = v;
            }
        __syncthreads();   // all waves done reading gs (g)
#pragma unroll
        for (int mt = 0; mt < 4; ++mt)
#pragma unroll
            for (int r = 0; r < 4; ++r)
                gs[(mt * 16 + quad * 4 + r) * 104 + c] = f2bf(x3[mt][r]);
        __syncthreads();
        f32x4 a2[4];
        mm96(f0p, a2);
        const float bf0c = bf0[c];
        __syncthreads();
#pragma unroll
        for (int mt = 0; mt < 4; ++mt)
#pragma unroll
            for (int r = 0; r < 4; ++r)
                gs[(mt * 16 + quad * 4 + r) * 104 + c] =
                    f2bf(fmaxf(a2[mt][r] + bf0c, 0.f));
        __syncthreads();
        f32x4 a3[4];
        mm96(f1p, a3);
        const float bf1c = bf1[c];
#pragma unroll
        for (int mt = 0; mt < 4; ++mt)
#pragma unroll
            for (int r = 0; r < 4; ++r) {
                int tg = t0 + mt * 16 + quad * 4 + r;
                if (tg < T_out)
                    out[base_out + (long)tg * 80 + c] = a3[mt][r] + bf1c;
            }
    }
}

// ============================================================================
// VQ via bf16 MFMA (unchanged from round 5, known-good).
// ============================================================================
__global__ __launch_bounds__(256, 2) void vq_mfma(
    const float* __restrict__ enc_s, const float* __restrict__ enc_q,
    const unsigned short* __restrict__ embp, const float* __restrict__ emb,
    const float* __restrict__ e2v,
    const float* __restrict__ w_lin, const float* __restrict__ b_lin,
    float* __restrict__ pred)
{
    __shared__ unsigned short xs[64 * 104];
    __shared__ unsigned short es[128 * 104];
    const uint4 z4 = make_uint4(0u, 0u, 0u, 0u);

    const int tid  = threadIdx.x;
    const int wave = tid >> 6;
    const int lane = tid & 63;
    const int m    = lane & 15;
    const int quad = lane >> 4;
    const int n    = blockIdx.y;
    const int t0   = blockIdx.x * 64;

    for (int u = tid; u < 64 * 20; u += 256) {
        int row = u / 20, c4 = u % 20;
        int t = t0 + row; if (t > 2039) t = 2039;
        float4 v = *(const float4*)(enc_s + ((long)n * 2040 + t) * 80 + c4 * 4);
        unsigned int s0 = (unsigned int)f2bf(v.x) | ((unsigned int)f2bf(v.y) << 16);
        unsigned int s1 = (unsigned int)f2bf(v.z) | ((unsigned int)f2bf(v.w) << 16);
        *(uint2*)&xs[row * 104 + c4 * 4] = make_uint2(s0, s1);
    }
    for (int u = tid; u < 128; u += 256)
        *(uint4*)&xs[(u >> 1) * 104 + 80 + (u & 1) * 8] = z4;
    __syncthreads();

    s16x8 af[3];
#pragma unroll
    for (int kb = 0; kb < 3; ++kb)
        af[kb] = *(const s16x8*)&xs[(wave * 16 + m) * 104 + kb * 32 + quad * 8];

    float best[4]; int bi[4];
#pragma unroll
    for (int r = 0; r < 4; ++r) { best[r] = 1e30f; bi[r] = 0; }

    for (int ch = 0; ch < 4; ++ch) {
        const int c0 = ch * 128;
        __syncthreads();
        for (int u = tid; u < 128 * 12; u += 256) {
            int el = u / 12, seg = u % 12;
            uint4 v = z4;
            if (seg < 10) v = *(const uint4*)(embp + (long)(c0 + el) * 80 + seg * 8);
            *(uint4*)&es[el * 104 + seg * 8] = v;
        }
        __syncthreads();

        f32x4 acc[8];
#pragma unroll
        for (int nt = 0; nt < 8; ++nt) acc[nt] = (f32x4){0.f, 0.f, 0.f, 0.f};
#pragma unroll
        for (int kb = 0; kb < 3; ++kb) {
            const int k0 = kb * 32 + quad * 8;
#pragma unroll
            for (int nt = 0; nt < 8; ++nt) {
                s16x8 b = *(const s16x8*)&es[(nt * 16 + m) * 104 + k0];
                acc[nt] = __builtin_amdgcn_mfma_f32_16x16x32_bf16(af[kb], b, acc[nt], 0, 0, 0);
            }
        }
#pragma unroll
        for (int nt = 0; nt < 8; ++nt) {
            const int e = c0 + nt * 16 + m;
            const float e2x = e2v[e];
#pragma unroll
            for (int r = 0; r < 4; ++r) {
                float s = fmaf(-2.0f, acc[nt][r], e2x);
                if (s < best[r]) { best[r] = s; bi[r] = e; }
            }
        }
    }

    __syncthreads();
    float* rb = (float*)es;
    int*   ri = (int*)es + 1088;
#pragma unroll
    for (int r = 0; r < 4; ++r) {
        int tl = wave * 16 + quad * 4 + r;
        rb[tl * 17 + m] = best[r];
        ri[tl * 17 + m] = bi[r];
    }
    __syncthreads();

    if (tid < 64) {
        const int t = t0 + tid;
        float b = rb[tid * 17]; int ix = ri[tid * 17];
#pragma unroll
        for (int j = 1; j < 16; ++j) {
            float v = rb[tid * 17 + j]; int iv = ri[tid * 17 + j];
            if (v < b || (v == b && iv < ix)) { b = v; ix = iv; }
        }
        if (t < 2040) {
            const float4* ev = (const float4*)(emb + (long)ix * 80);
            const bool hasq = (t < 2016);
            const float4* qv = hasq
                ? (const float4*)(enc_q + ((long)n * 504 + (t % 504)) * 80) : nullptr;
            float p0 = b_lin[0], p1 = b_lin[1];
#pragma unroll
            for (int i = 0; i < 20; ++i) {
                float4 e4 = ev[i];
                float4 q4 = hasq ? qv[i] : make_float4(0.f, 0.f, 0.f, 0.f);
                float4 w0 = *(const float4*)(w_lin + 4 * i);
                float4 w1 = *(const float4*)(w_lin + 80 + 4 * i);
                float sx = e4.x + q4.x, sy = e4.y + q4.y;
                float sz = e4.z + q4.z, sw = e4.w + q4.w;
                p0 = fmaf(sx, w0.x, p0); p1 = fmaf(sx, w1.x, p1);
                p0 = fmaf(sy, w0.y, p0); p1 = fmaf(sy, w1.y, p1);
                p0 = fmaf(sz, w0.z, p0); p1 = fmaf(sz, w1.z, p1);
                p0 = fmaf(sw, w0.w, p0); p1 = fmaf(sw, w1.w, p1);
            }
            long o = ((long)n * 2040 + t) * 2;
            pred[o]     = fast_tanh(p0);
            pred[o + 1] = fast_tanh(p1);
        }
    }
}

// ============================================================================
__global__ __launch_bounds__(256) void max_red(const float* __restrict__ pred,
                                               float* __restrict__ out)
{
    __shared__ float s0[256], s1[256];
    const int n = blockIdx.x, tid = threadIdx.x;
    float m0 = -1e30f, m1 = -1e30f;
    for (int t = tid; t < 2040; t += 256) {
        long o = ((long)n * 2040 + t) * 2;
        m0 = fmaxf(m0, pred[o]);
        m1 = fmaxf(m1, pred[o + 1]);
    }
    s0[tid] = m0; s1[tid] = m1;
    __syncthreads();
    for (int st = 128; st > 0; st >>= 1) {
        if (tid < st) {
            s0[tid] = fmaxf(s0[tid], s0[tid + st]);
            s1[tid] = fmaxf(s1[tid], s1[tid + st]);
        }
        __syncthreads();
    }
    if (tid == 0) { out[n * 2] = s0[0]; out[n * 2 + 1] = s1[0]; }
}

// ============================================================================
extern "C" void kernel_launch(void* const* d_in, const int* in_sizes, int n_in,
                              void* d_out, int out_size, void* d_ws, size_t ws_size,
                              hipStream_t stream)
{
    const float* search = (const float*)d_in[0];
    const float* query  = (const float*)d_in[1];
    const float* w_wide = (const float*)d_in[2];
    const float* b_wide = (const float*)d_in[3];
    const float* w_1x1  = (const float*)d_in[4];
    const float* b_1x1  = (const float*)d_in[5];
    const float* w_f0   = (const float*)d_in[6];
    const float* b_f0   = (const float*)d_in[7];
    const float* w_f1   = (const float*)d_in[8];
    const float* b_f1   = (const float*)d_in[9];
    const float* emb    = (const float*)d_in[10];
    const float* w_lin  = (const float*)d_in[11];
    const float* b_lin  = (const float*)d_in[12];
    float* out = (float*)d_out;
    float* ws  = (float*)d_ws;

    // fp32 flow: L0: in->A/QA; L1: A->B/QB; L2: B->C/QC; L3: C->B(encS)/QB(encQ);
    // vq: pred->C.
    float* A  = ws;                 // 5,241,600
    float* B  = A  + 5241600;       // 2,618,880
    float* C  = B  + 2618880;       // 2,618,880
    float* QA = C  + 2618880;       // 1,309,440
    float* QB = QA + 1309440;       //   652,800
    float* QC = QB + 652800;        //   652,800
    unsigned short* WWp = (unsigned short*)(QC + 652800);
    unsigned short* W1p = WWp + 204800;        // 4 x 80 x 96
    unsigned short* F0p = W1p + 30720;         // 80 x 96
    unsigned short* F1p = F0p + 7680;
    unsigned short* EMp = F1p + 7680;          // 512 x 80
    float* e2b = (float*)(EMp + 40960);        // 512

    const dim3 blk(320);
    auto nb = [](int T) { return (T + 63) / 64; };

    pack_all<<<dim3(1142), dim3(256), 0, stream>>>(w_wide, w_1x1, w_f0, w_f1, emb,
                                                   WWp, W1p, F0p, F1p, EMp, e2b);

    enc_layer<2, false, false><<<dim3(nb(4095) + nb(1023), NBATCH), blk, 0, stream>>>(
        search, query, WWp, b_wide, W1p, b_1x1, nullptr, nullptr, nullptr, nullptr,
        A, QA, 8192, 4095, 2048, 1023, nb(4095));
    enc_layer<2, true, false><<<dim3(nb(2046) + nb(510), NBATCH), blk, 0, stream>>>(
        A, QA, WWp + 51200, b_wide + 160, W1p + 7680, b_1x1 + 80,
        nullptr, nullptr, nullptr, nullptr,
        B, QB, 4095, 2046, 1023, 510, nb(2046));
    enc_layer<1, true, false><<<dim3(nb(2043) + nb(507), NBATCH), blk, 0, stream>>>(
        B, QB, WWp + 102400, b_wide + 320, W1p + 15360, b_1x1 + 160,
        nullptr, nullptr, nullptr, nullptr,
        C, QC, 2046, 2043, 510, 507, nb(2043));
    enc_layer<1, true, true><<<dim3(nb(2040) + nb(504), NBATCH), blk, 0, stream>>>(
        C, QC, WWp + 153600, b_wide + 480, W1p + 23040, b_1x1 + 240,
        F0p, b_f0, F1p, b_f1,
        B, QB, 2043, 2040, 507, 504, nb(2040));

    vq_mfma<<<dim3(32, NBATCH), dim3(256), 0, stream>>>(B, QB, EMp, emb, e2b,
                                                        w_lin, b_lin, C);
    max_red<<<dim3(NBATCH), dim3(256), 0, stream>>>(C, out);
}